// Round 1
// baseline (110.873 us; speedup 1.0000x reference)
//
#include <hip/hip_runtime.h>
#include <math.h>

#define NBATCH 256
#define NPTS   4096
#define NT     256
#define PPT    (NPTS / NT)

__device__ __forceinline__ void inv3x3d(const float* __restrict__ Km, double* Ki) {
  double a = Km[0], bb = Km[1], c = Km[2];
  double d = Km[3], e  = Km[4], f = Km[5];
  double g = Km[6], h  = Km[7], i = Km[8];
  double C00 =  e*i - f*h;
  double C01 = -(d*i - f*g);
  double C02 =  d*h - e*g;
  double det = a*C00 + bb*C01 + c*C02;
  double rd = 1.0/det;
  Ki[0] = C00*rd; Ki[1] = -(bb*i - c*h)*rd; Ki[2] =  (bb*f - c*e)*rd;
  Ki[3] = C01*rd; Ki[4] =  (a*i  - c*g)*rd; Ki[5] = -(a*f  - c*d)*rd;
  Ki[6] = C02*rd; Ki[7] = -(a*h - bb*g)*rd; Ki[8] =  (a*e  - bb*d)*rd;
}

__global__ __launch_bounds__(NT, 1)
void pose_kernel(const float* __restrict__ kpts0,
                 const float* __restrict__ kpts1,
                 const float* __restrict__ conf,
                 const float* __restrict__ t_scale,
                 const float* __restrict__ Kmat,
                 float* __restrict__ out)
{
  const int b    = blockIdx.x;
  const int tid  = threadIdx.x;
  const int lane = tid & 63;
  const int wv   = tid >> 6;

  __shared__ double red[4][45];
  __shared__ double sM[45];
  __shared__ double sR[21];       // R1(9), R2(9), t(3)
  __shared__ double sscore[4][4];

  double Ki0[9], Ki1[9];
  inv3x3d(Kmat + (size_t)b*18,     Ki0);
  inv3x3d(Kmat + (size_t)b*18 + 9, Ki1);

  const float2* k0p = (const float2*)kpts0 + (size_t)b*NPTS;
  const float2* k1p = (const float2*)kpts1 + (size_t)b*NPTS;
  const float*  cp  = conf + (size_t)b*NPTS;

  // ---------------- Phase 1: M = sum_n w * X X^T (45 unique entries) --------
  double acc[45];
#pragma unroll
  for (int j=0;j<45;j++) acc[j] = 0.0;

  for (int p=0;p<PPT;p++) {
    const int i = tid + p*NT;
    const float2 q0 = k0p[i];
    const float2 q1 = k1p[i];
    const double w  = (double)cp[i];
    double x0[3], x1[3];
    x0[0] = Ki0[0]*q0.x + Ki0[1]*q0.y + Ki0[2];
    x0[1] = Ki0[3]*q0.x + Ki0[4]*q0.y + Ki0[5];
    x0[2] = Ki0[6]*q0.x + Ki0[7]*q0.y + Ki0[8];
    x1[0] = Ki1[0]*q1.x + Ki1[1]*q1.y + Ki1[2];
    x1[1] = Ki1[3]*q1.x + Ki1[4]*q1.y + Ki1[5];
    x1[2] = Ki1[6]*q1.x + Ki1[7]*q1.y + Ki1[8];
    double X[9];
#pragma unroll
    for (int ii=0; ii<3; ii++)
#pragma unroll
      for (int jj=0; jj<3; jj++)
        X[ii*3+jj] = x1[ii]*x0[jj];
    double wX[9];
#pragma unroll
    for (int j=0;j<9;j++) wX[j] = w*X[j];
    int k = 0;
#pragma unroll
    for (int r=0;r<9;r++)
#pragma unroll
      for (int c=r;c<9;c++) { acc[k] = fma(wX[r], X[c], acc[k]); k++; }
  }

  // wave butterfly reduce, then cross-wave via LDS
#pragma unroll
  for (int j=0;j<45;j++) {
    double v = acc[j];
#pragma unroll
    for (int off=32; off>0; off>>=1) v += __shfl_xor(v, off, 64);
    acc[j] = v;
  }
  if (lane == 0) {
#pragma unroll
    for (int j=0;j<45;j++) red[wv][j] = acc[j];
  }
  __syncthreads();
  if (tid < 45) sM[tid] = red[0][tid] + red[1][tid] + red[2][tid] + red[3][tid];
  __syncthreads();

  // ---------------- Phase 2: eig-min(M) -> E -> SVD -> candidates (tid 0) ---
  double R1a[9] = {0}, R2a[9] = {0}, ta[3] = {0};
  if (tid == 0) {
    // full symmetric load (upper entries DCE'd by Cholesky's lower-only reads)
    double A[9][9];
#pragma unroll
    for (int r=0;r<9;r++)
#pragma unroll
      for (int c=0;c<9;c++) {
        const int rr = (r<c)?r:c, cc = (r<c)?c:r;
        A[r][c] = sM[rr*9 - (rr*(rr-1))/2 + (cc-rr)];
      }
    // Cholesky A = L L^T (lower, in place). M is PD: lambda_min ~ 12.
    double dinv[9];
#pragma unroll
    for (int k=0;k<9;k++) {
      double s = A[k][k];
#pragma unroll
      for (int j=0;j<k;j++) s -= A[k][j]*A[k][j];
      double l = sqrt(fmax(s, 1e-30));
      A[k][k] = l;
      dinv[k] = 1.0/l;
#pragma unroll
      for (int i2=k+1;i2<9;i2++) {
        double s2 = A[i2][k];
#pragma unroll
        for (int j=0;j<k;j++) s2 -= A[i2][j]*A[k][j];
        A[i2][k] = s2*dinv[k];
      }
    }
    // inverse iteration: converges at (lmin/l2)^k ~ 0.5626^24 ~ 1e-6
    double v[9];
#pragma unroll
    for (int j=0;j<9;j++) v[j] = 0.125;
    v[4] = 1.0;   // population eigvec ~ e4
    for (int it=0; it<24; it++) {
      double y[9], z[9];
#pragma unroll
      for (int i2=0;i2<9;i2++) {
        double s = v[i2];
#pragma unroll
        for (int j=0;j<i2;j++) s -= A[i2][j]*y[j];
        y[i2] = s*dinv[i2];
      }
#pragma unroll
      for (int i2=8;i2>=0;i2--) {
        double s = y[i2];
#pragma unroll
        for (int j=i2+1;j<9;j++) s -= A[j][i2]*z[j];
        z[i2] = s*dinv[i2];
      }
      double nn = 0.0;
#pragma unroll
      for (int j=0;j<9;j++) nn += z[j]*z[j];
      double rn = 1.0/sqrt(nn);
#pragma unroll
      for (int j=0;j<9;j++) v[j] = z[j]*rn;
    }
    // E = reshape(v, 3x3)
    double E0[3][3];
#pragma unroll
    for (int ii=0;ii<3;ii++)
#pragma unroll
      for (int jj=0;jj<3;jj++) E0[ii][jj] = v[ii*3+jj];
    // SVD via Jacobi on G = E^T E (V), then U by projection + cross.
    double G[3][3];
#pragma unroll
    for (int a2=0;a2<3;a2++)
#pragma unroll
      for (int b2=0;b2<3;b2++)
        G[a2][b2] = E0[0][a2]*E0[0][b2] + E0[1][a2]*E0[1][b2] + E0[2][a2]*E0[2][b2];
    double Vv[3][3] = {{1,0,0},{0,1,0},{0,0,1}};
#define JROT(P,Q,RR) do { \
      double apq = G[P][Q]; \
      if (fabs(apq) > 1e-300) { \
        double app = G[P][P], aqq = G[Q][Q]; \
        double tau = (aqq - app) / (2.0*apq); \
        double tt = ((tau >= 0.0) ? 1.0 : -1.0) / (fabs(tau) + sqrt(1.0 + tau*tau)); \
        double cc_ = 1.0/sqrt(1.0 + tt*tt); \
        double ss_ = tt*cc_; \
        G[P][P] = app - tt*apq; \
        G[Q][Q] = aqq + tt*apq; \
        G[P][Q] = 0.0; G[Q][P] = 0.0; \
        double grp = G[RR][P], grq = G[RR][Q]; \
        G[RR][P] = cc_*grp - ss_*grq; G[P][RR] = G[RR][P]; \
        G[RR][Q] = ss_*grp + cc_*grq; G[Q][RR] = G[RR][Q]; \
        double v0p = Vv[0][P], v0q = Vv[0][Q]; \
        Vv[0][P] = cc_*v0p - ss_*v0q; Vv[0][Q] = ss_*v0p + cc_*v0q; \
        double v1p = Vv[1][P], v1q = Vv[1][Q]; \
        Vv[1][P] = cc_*v1p - ss_*v1q; Vv[1][Q] = ss_*v1p + cc_*v1q; \
        double v2p = Vv[2][P], v2q = Vv[2][Q]; \
        Vv[2][P] = cc_*v2p - ss_*v2q; Vv[2][Q] = ss_*v2p + cc_*v2q; \
      } } while(0)
    for (int sw=0; sw<8; sw++) { JROT(0,1,2); JROT(0,2,1); JROT(1,2,0); }
#undef JROT
    double lam[3] = {G[0][0], G[1][1], G[2][2]};
#define CSWAP(A_,B_) if (lam[A_] < lam[B_]) { \
      double tl = lam[A_]; lam[A_] = lam[B_]; lam[B_] = tl; \
      double t0_ = Vv[0][A_]; Vv[0][A_] = Vv[0][B_]; Vv[0][B_] = t0_; \
      double t1_ = Vv[1][A_]; Vv[1][A_] = Vv[1][B_]; Vv[1][B_] = t1_; \
      double t2_ = Vv[2][A_]; Vv[2][A_] = Vv[2][B_]; Vv[2][B_] = t2_; }
    CSWAP(0,1); CSWAP(0,2); CSWAP(1,2);
#undef CSWAP
    double u1[3], u2[3], u3[3];
#pragma unroll
    for (int i3=0;i3<3;i3++)
      u1[i3] = E0[i3][0]*Vv[0][0] + E0[i3][1]*Vv[1][0] + E0[i3][2]*Vv[2][0];
    double n1 = 1.0/sqrt(fmax(u1[0]*u1[0]+u1[1]*u1[1]+u1[2]*u1[2], 1e-300));
#pragma unroll
    for (int i3=0;i3<3;i3++) u1[i3] *= n1;
#pragma unroll
    for (int i3=0;i3<3;i3++)
      u2[i3] = E0[i3][0]*Vv[0][1] + E0[i3][1]*Vv[1][1] + E0[i3][2]*Vv[2][1];
    double d12 = u1[0]*u2[0]+u1[1]*u2[1]+u1[2]*u2[2];
#pragma unroll
    for (int i3=0;i3<3;i3++) u2[i3] -= d12*u1[i3];
    double n2 = 1.0/sqrt(fmax(u2[0]*u2[0]+u2[1]*u2[1]+u2[2]*u2[2], 1e-300));
#pragma unroll
    for (int i3=0;i3<3;i3++) u2[i3] *= n2;
    u3[0] = u1[1]*u2[2] - u1[2]*u2[1];
    u3[1] = u1[2]*u2[0] - u1[0]*u2[2];
    u3[2] = u1[0]*u2[1] - u1[1]*u2[0];
    // U W V^T = [u2,-u1,u3] V^T ;  U W^T V^T = [-u2,u1,u3] V^T
#pragma unroll
    for (int i3=0;i3<3;i3++)
#pragma unroll
      for (int j3=0;j3<3;j3++) {
        double m  = u3[i3]*Vv[j3][2];
        double pA = u2[i3]*Vv[j3][0] - u1[i3]*Vv[j3][1];
        R1a[i3*3+j3] = pA + m;
        R2a[i3*3+j3] = m - pA;
      }
    double det1 = R1a[0]*(R1a[4]*R1a[8]-R1a[5]*R1a[7])
                - R1a[1]*(R1a[3]*R1a[8]-R1a[5]*R1a[6])
                + R1a[2]*(R1a[3]*R1a[7]-R1a[4]*R1a[6]);
    double det2 = R2a[0]*(R2a[4]*R2a[8]-R2a[5]*R2a[7])
                - R2a[1]*(R2a[3]*R2a[8]-R2a[5]*R2a[6])
                + R2a[2]*(R2a[3]*R2a[7]-R2a[4]*R2a[6]);
    double sg1 = (det1 < 0.0) ? -1.0 : 1.0;
    double sg2 = (det2 < 0.0) ? -1.0 : 1.0;
#pragma unroll
    for (int j3=0;j3<9;j3++) { R1a[j3] *= sg1; R2a[j3] *= sg2; }
    ta[0] = u3[0]; ta[1] = u3[1]; ta[2] = u3[2];
#pragma unroll
    for (int j3=0;j3<9;j3++) { sR[j3] = R1a[j3]; sR[9+j3] = R2a[j3]; }
    sR[18] = ta[0]; sR[19] = ta[1]; sR[20] = ta[2];
  }
  __syncthreads();

  // ---------------- Phase 3: cheirality scores for 4 candidates -------------
  double r1[9], r2[9], tv3[3];
#pragma unroll
  for (int j=0;j<9;j++) { r1[j] = sR[j]; r2[j] = sR[9+j]; }
  tv3[0] = sR[18]; tv3[1] = sR[19]; tv3[2] = sR[20];

  double sc[4] = {0.0, 0.0, 0.0, 0.0};
  for (int p=0;p<PPT;p++) {
    const int i = tid + p*NT;
    const float2 q0 = k0p[i];     // L1/L2-hot re-read
    const float2 q1 = k1p[i];
    const double w  = (double)cp[i];
    double x0[3], x1[3];
    x0[0] = Ki0[0]*q0.x + Ki0[1]*q0.y + Ki0[2];
    x0[1] = Ki0[3]*q0.x + Ki0[4]*q0.y + Ki0[5];
    x0[2] = Ki0[6]*q0.x + Ki0[7]*q0.y + Ki0[8];
    x1[0] = Ki1[0]*q1.x + Ki1[1]*q1.y + Ki1[2];
    x1[1] = Ki1[3]*q1.x + Ki1[4]*q1.y + Ki1[5];
    x1[2] = Ki1[6]*q1.x + Ki1[7]*q1.y + Ki1[8];
    const double bb2 = x1[0]*x1[0]+x1[1]*x1[1]+x1[2]*x1[2];
    const double bt  = x1[0]*tv3[0]+x1[1]*tv3[1]+x1[2]*tv3[2];
    {
      double a0 = r1[0]*x0[0]+r1[1]*x0[1]+r1[2]*x0[2];
      double a1 = r1[3]*x0[0]+r1[4]*x0[1]+r1[5]*x0[2];
      double a2 = r1[6]*x0[0]+r1[7]*x0[1]+r1[8]*x0[2];
      double aa = a0*a0+a1*a1+a2*a2;
      double ab = a0*x1[0]+a1*x1[1]+a2*x1[2];
      double at = a0*tv3[0]+a1*tv3[1]+a2*tv3[2];
      double n0v = ab*bt - at*bb2;      // d0 * det (det > 0)
      double n1v = aa*bt - ab*at;       // d1 * det
      if (n0v > 0.0 && n1v > 0.0) sc[0] += w;   // (R1, +t)
      if (n0v < 0.0 && n1v < 0.0) sc[1] += w;   // (R1, -t): d -> -d
    }
    {
      double a0 = r2[0]*x0[0]+r2[1]*x0[1]+r2[2]*x0[2];
      double a1 = r2[3]*x0[0]+r2[4]*x0[1]+r2[5]*x0[2];
      double a2 = r2[6]*x0[0]+r2[7]*x0[1]+r2[8]*x0[2];
      double aa = a0*a0+a1*a1+a2*a2;
      double ab = a0*x1[0]+a1*x1[1]+a2*x1[2];
      double at = a0*tv3[0]+a1*tv3[1]+a2*tv3[2];
      double n0v = ab*bt - at*bb2;
      double n1v = aa*bt - ab*at;
      if (n0v > 0.0 && n1v > 0.0) sc[2] += w;   // (R2, +t)
      if (n0v < 0.0 && n1v < 0.0) sc[3] += w;   // (R2, -t)
    }
  }
#pragma unroll
  for (int c=0;c<4;c++) {
    double vv = sc[c];
#pragma unroll
    for (int off=32; off>0; off>>=1) vv += __shfl_xor(vv, off, 64);
    sc[c] = vv;
  }
  if (lane == 0) {
#pragma unroll
    for (int c=0;c<4;c++) sscore[wv][c] = sc[c];
  }
  __syncthreads();

  // ---------------- Phase 4: argmax + assemble T01 / T10 (tid 0) ------------
  if (tid == 0) {
    double st0 = sscore[0][0]+sscore[1][0]+sscore[2][0]+sscore[3][0];
    double st1 = sscore[0][1]+sscore[1][1]+sscore[2][1]+sscore[3][1];
    double st2 = sscore[0][2]+sscore[1][2]+sscore[2][2]+sscore[3][2];
    double st3 = sscore[0][3]+sscore[1][3]+sscore[2][3]+sscore[3][3];
    int bestc = 0; double bs = st0;
    if (st1 > bs) { bs = st1; bestc = 1; }   // strict > keeps first on tie (argmax)
    if (st2 > bs) { bs = st2; bestc = 2; }
    if (st3 > bs) { bs = st3; bestc = 3; }
    double Rb[9];
#pragma unroll
    for (int j=0;j<9;j++) Rb[j] = (bestc < 2) ? R1a[j] : R2a[j];
    const double sg = (bestc & 1) ? -1.0 : 1.0;
    const double ts = (double)t_scale[(size_t)b*2];
    const double t0 = sg*ta[0]*ts, t1 = sg*ta[1]*ts, t2 = sg*ta[2]*ts;
    float* o = out + (size_t)b*32;
    // T01 = [R | t_sc ; 0 0 0 1]
    o[0]=(float)Rb[0]; o[1]=(float)Rb[1]; o[2] =(float)Rb[2]; o[3] =(float)t0;
    o[4]=(float)Rb[3]; o[5]=(float)Rb[4]; o[6] =(float)Rb[5]; o[7] =(float)t1;
    o[8]=(float)Rb[6]; o[9]=(float)Rb[7]; o[10]=(float)Rb[8]; o[11]=(float)t2;
    o[12]=0.f; o[13]=0.f; o[14]=0.f; o[15]=1.f;
    // T10 = [R^T | -R^T t_sc ; 0 0 0 1]
    const double ti0 = -(Rb[0]*t0 + Rb[3]*t1 + Rb[6]*t2);
    const double ti1 = -(Rb[1]*t0 + Rb[4]*t1 + Rb[7]*t2);
    const double ti2 = -(Rb[2]*t0 + Rb[5]*t1 + Rb[8]*t2);
    o[16]=(float)Rb[0]; o[17]=(float)Rb[3]; o[18]=(float)Rb[6]; o[19]=(float)ti0;
    o[20]=(float)Rb[1]; o[21]=(float)Rb[4]; o[22]=(float)Rb[7]; o[23]=(float)ti1;
    o[24]=(float)Rb[2]; o[25]=(float)Rb[5]; o[26]=(float)Rb[8]; o[27]=(float)ti2;
    o[28]=0.f; o[29]=0.f; o[30]=0.f; o[31]=1.f;
  }
}

extern "C" void kernel_launch(void* const* d_in, const int* in_sizes, int n_in,
                              void* d_out, int out_size, void* d_ws, size_t ws_size,
                              hipStream_t stream) {
  (void)in_sizes; (void)n_in; (void)out_size; (void)d_ws; (void)ws_size;
  const float* kpts0   = (const float*)d_in[0];
  const float* kpts1   = (const float*)d_in[1];
  const float* conf    = (const float*)d_in[2];
  const float* tscale  = (const float*)d_in[3];
  const float* K       = (const float*)d_in[4];
  // d_in[5] = gt_pose_0to1 (unused by the reference output)
  float* outp = (float*)d_out;
  pose_kernel<<<dim3(NBATCH), dim3(NT), 0, stream>>>(kpts0, kpts1, conf, tscale, K, outp);
}

// Round 2
// 101.770 us; speedup vs baseline: 1.0894x; 1.0894x over previous
//
#include <hip/hip_runtime.h>
#include <math.h>

#define NBATCH 256
#define NPTS   4096

// ---------------------------------------------------------------------------
// fp64 3x3 inverse (K is fp32 in memory)
// ---------------------------------------------------------------------------
__device__ __forceinline__ void inv3x3d(const float* __restrict__ Km, double* Ki) {
  double a = Km[0], bb = Km[1], c = Km[2];
  double d = Km[3], e  = Km[4], f = Km[5];
  double g = Km[6], h  = Km[7], i = Km[8];
  double C00 =  e*i - f*h;
  double C01 = -(d*i - f*g);
  double C02 =  d*h - e*g;
  double det = a*C00 + bb*C01 + c*C02;
  double rd = 1.0/det;
  Ki[0] = C00*rd; Ki[1] = -(bb*i - c*h)*rd; Ki[2] =  (bb*f - c*e)*rd;
  Ki[3] = C01*rd; Ki[4] =  (a*i  - c*g)*rd; Ki[5] = -(a*f  - c*d)*rd;
  Ki[6] = C02*rd; Ki[7] = -(a*h - bb*g)*rd; Ki[8] =  (a*e  - bb*d)*rd;
}

// packed-lower index, r >= c
#define IDX(r,c)   ((r)*((r)+1)/2+(c))
// packed-upper index (K1 storage order), r <= c
#define UPIDX(r,c) ((r)*9 - ((r)*((r)-1))/2 + ((c)-(r)))

// ===========================================================================
// K1: M[b] = sum_n w * X X^T   (45 unique upper-tri entries, fp32 partials)
// grid 256 x 512
// ===========================================================================
#define K1_T   512
#define K1_PPT (NPTS / K1_T)

__global__ __launch_bounds__(K1_T, 2)
void k1_reduce(const float* __restrict__ kpts0,
               const float* __restrict__ kpts1,
               const float* __restrict__ conf,
               const float* __restrict__ Kmat,
               double* __restrict__ Mws)
{
  const int b    = blockIdx.x;
  const int tid  = threadIdx.x;
  const int lane = tid & 63;
  const int wv   = tid >> 6;

  __shared__ double red[K1_T/64][45];

  double Kd[9];
  float Ki0[9], Ki1[9];
  inv3x3d(Kmat + (size_t)b*18, Kd);
#pragma unroll
  for (int j=0;j<9;j++) Ki0[j] = (float)Kd[j];
  inv3x3d(Kmat + (size_t)b*18 + 9, Kd);
#pragma unroll
  for (int j=0;j<9;j++) Ki1[j] = (float)Kd[j];

  const float2* k0p = (const float2*)kpts0 + (size_t)b*NPTS;
  const float2* k1p = (const float2*)kpts1 + (size_t)b*NPTS;
  const float*  cp  = conf + (size_t)b*NPTS;

  float acc[45];
#pragma unroll
  for (int j=0;j<45;j++) acc[j] = 0.f;

  for (int p=0;p<K1_PPT;p++) {
    const int i = tid + p*K1_T;
    const float2 q0 = k0p[i];
    const float2 q1 = k1p[i];
    const float  w  = cp[i];
    float x0[3], x1[3];
    x0[0] = fmaf(Ki0[0],q0.x, fmaf(Ki0[1],q0.y, Ki0[2]));
    x0[1] = fmaf(Ki0[3],q0.x, fmaf(Ki0[4],q0.y, Ki0[5]));
    x0[2] = fmaf(Ki0[6],q0.x, fmaf(Ki0[7],q0.y, Ki0[8]));
    x1[0] = fmaf(Ki1[0],q1.x, fmaf(Ki1[1],q1.y, Ki1[2]));
    x1[1] = fmaf(Ki1[3],q1.x, fmaf(Ki1[4],q1.y, Ki1[5]));
    x1[2] = fmaf(Ki1[6],q1.x, fmaf(Ki1[7],q1.y, Ki1[8]));
    float X[9], wX[9];
#pragma unroll
    for (int ii=0; ii<3; ii++)
#pragma unroll
      for (int jj=0; jj<3; jj++)
        X[ii*3+jj] = x1[ii]*x0[jj];
#pragma unroll
    for (int j=0;j<9;j++) wX[j] = w*X[j];
    int k = 0;
#pragma unroll
    for (int r=0;r<9;r++)
#pragma unroll
      for (int c=r;c<9;c++) { acc[k] = fmaf(wX[r], X[c], acc[k]); k++; }
  }

  // fp32 butterfly within wave (pairwise summation: error ~log2(64)*eps)
#pragma unroll
  for (int j=0;j<45;j++) {
    float v = acc[j];
#pragma unroll
    for (int off=32; off>0; off>>=1) v += __shfl_xor(v, off, 64);
    acc[j] = v;
  }
  if (lane == 0) {
#pragma unroll
    for (int j=0;j<45;j++) red[wv][j] = (double)acc[j];
  }
  __syncthreads();
  if (tid < 45) {
    double s = 0.0;
#pragma unroll
    for (int wq=0; wq<K1_T/64; wq++) s += red[wq][tid];
    Mws[(size_t)b*45 + tid] = s;
  }
}

// ===========================================================================
// K2: per-batch (one lane per batch): min-eigvec of M -> E -> SVD -> R1,R2,t
// grid 4 x 64
// ===========================================================================
__global__ __launch_bounds__(64, 1)
void k2_solve(const double* __restrict__ Mws,
              float* __restrict__ Rws)
{
  const int b = blockIdx.x*64 + threadIdx.x;
  const double* Mb = Mws + (size_t)b*45;

  // load packed-lower from packed-upper storage
  double L[45];
#pragma unroll
  for (int r=0;r<9;r++)
#pragma unroll
    for (int c=0;c<=r;c++)
      L[IDX(r,c)] = Mb[UPIDX(c,r)];

  // Cholesky M = L L^T (packed lower, in place). M is PD (lmin ~ 12).
  double dinv[9];
#pragma unroll
  for (int k=0;k<9;k++) {
    double s = L[IDX(k,k)];
#pragma unroll
    for (int j=0;j<k;j++) s -= L[IDX(k,j)]*L[IDX(k,j)];
    double l = sqrt(fmax(s, 1e-30));
    L[IDX(k,k)] = l;
    dinv[k] = 1.0/l;
#pragma unroll
    for (int i2=k+1;i2<9;i2++) {
      double s2 = L[IDX(i2,k)];
#pragma unroll
      for (int j=0;j<k;j++) s2 -= L[IDX(i2,j)]*L[IDX(k,j)];
      L[IDX(i2,k)] = s2*dinv[k];
    }
  }

  // W = L^{-1} (packed lower)
  double W[45];
#pragma unroll
  for (int j=0;j<9;j++) {
    W[IDX(j,j)] = dinv[j];
#pragma unroll
    for (int i2=j+1;i2<9;i2++) {
      double s = 0.0;
#pragma unroll
      for (int k=j;k<i2;k++) s += L[IDX(i2,k)]*W[IDX(k,j)];
      W[IDX(i2,j)] = -s*dinv[i2];
    }
  }

  // B = W^T W = M^{-1} (packed lower)
  double Bm[45];
#pragma unroll
  for (int i2=0;i2<9;i2++)
#pragma unroll
    for (int j=0;j<=i2;j++) {
      double s = 0.0;
#pragma unroll
      for (int k=i2;k<9;k++) s += W[IDX(k,i2)]*W[IDX(k,j)];
      Bm[IDX(i2,j)] = s;
    }

  // power iteration on B (= inverse iteration on M). ratio (lmin/l2)^20 ~ 1e-5.
  // no renorm: values shrink by ~lmin^-1 per iter; fp64 exponent absorbs it.
  double v[9];
#pragma unroll
  for (int j=0;j<9;j++) v[j] = 0.125;
  v[4] = 1.0;
  for (int it=0; it<20; it++) {
    double y[9];
#pragma unroll
    for (int i2=0;i2<9;i2++) {
      double s = 0.0;
#pragma unroll
      for (int j=0;j<9;j++) {
        const int rr = (i2>j)?i2:j, cc = (i2>j)?j:i2;
        s = fma(Bm[IDX(rr,cc)], v[j], s);
      }
      y[i2] = s;
    }
#pragma unroll
    for (int j=0;j<9;j++) v[j] = y[j];
  }
  {
    double nn = 0.0;
#pragma unroll
    for (int j=0;j<9;j++) nn += v[j]*v[j];
    double rn = 1.0/sqrt(nn);
#pragma unroll
    for (int j=0;j<9;j++) v[j] *= rn;
  }

  // E = reshape(v,3,3); SVD via Jacobi on G=E^T E (V), U by projection+cross
  double E0[3][3];
#pragma unroll
  for (int ii=0;ii<3;ii++)
#pragma unroll
    for (int jj=0;jj<3;jj++) E0[ii][jj] = v[ii*3+jj];
  double G[3][3];
#pragma unroll
  for (int a2=0;a2<3;a2++)
#pragma unroll
    for (int b2=0;b2<3;b2++)
      G[a2][b2] = E0[0][a2]*E0[0][b2] + E0[1][a2]*E0[1][b2] + E0[2][a2]*E0[2][b2];
  double Vv[3][3] = {{1,0,0},{0,1,0},{0,0,1}};
#define JROT(P,Q,RR) do { \
    double apq = G[P][Q]; \
    if (fabs(apq) > 1e-300) { \
      double app = G[P][P], aqq = G[Q][Q]; \
      double tau = (aqq - app) / (2.0*apq); \
      double tt = ((tau >= 0.0) ? 1.0 : -1.0) / (fabs(tau) + sqrt(1.0 + tau*tau)); \
      double cc_ = 1.0/sqrt(1.0 + tt*tt); \
      double ss_ = tt*cc_; \
      G[P][P] = app - tt*apq; \
      G[Q][Q] = aqq + tt*apq; \
      G[P][Q] = 0.0; G[Q][P] = 0.0; \
      double grp = G[RR][P], grq = G[RR][Q]; \
      G[RR][P] = cc_*grp - ss_*grq; G[P][RR] = G[RR][P]; \
      G[RR][Q] = ss_*grp + cc_*grq; G[Q][RR] = G[RR][Q]; \
      double v0p = Vv[0][P], v0q = Vv[0][Q]; \
      Vv[0][P] = cc_*v0p - ss_*v0q; Vv[0][Q] = ss_*v0p + cc_*v0q; \
      double v1p = Vv[1][P], v1q = Vv[1][Q]; \
      Vv[1][P] = cc_*v1p - ss_*v1q; Vv[1][Q] = ss_*v1p + cc_*v1q; \
      double v2p = Vv[2][P], v2q = Vv[2][Q]; \
      Vv[2][P] = cc_*v2p - ss_*v2q; Vv[2][Q] = ss_*v2p + cc_*v2q; \
    } } while(0)
  for (int sw=0; sw<6; sw++) { JROT(0,1,2); JROT(0,2,1); JROT(1,2,0); }
#undef JROT
  double lam[3] = {G[0][0], G[1][1], G[2][2]};
#define CSWAP(A_,B_) if (lam[A_] < lam[B_]) { \
    double tl = lam[A_]; lam[A_] = lam[B_]; lam[B_] = tl; \
    double t0_ = Vv[0][A_]; Vv[0][A_] = Vv[0][B_]; Vv[0][B_] = t0_; \
    double t1_ = Vv[1][A_]; Vv[1][A_] = Vv[1][B_]; Vv[1][B_] = t1_; \
    double t2_ = Vv[2][A_]; Vv[2][A_] = Vv[2][B_]; Vv[2][B_] = t2_; }
  CSWAP(0,1); CSWAP(0,2); CSWAP(1,2);
#undef CSWAP
  double u1[3], u2[3], u3[3];
#pragma unroll
  for (int i3=0;i3<3;i3++)
    u1[i3] = E0[i3][0]*Vv[0][0] + E0[i3][1]*Vv[1][0] + E0[i3][2]*Vv[2][0];
  double n1 = 1.0/sqrt(fmax(u1[0]*u1[0]+u1[1]*u1[1]+u1[2]*u1[2], 1e-300));
#pragma unroll
  for (int i3=0;i3<3;i3++) u1[i3] *= n1;
#pragma unroll
  for (int i3=0;i3<3;i3++)
    u2[i3] = E0[i3][0]*Vv[0][1] + E0[i3][1]*Vv[1][1] + E0[i3][2]*Vv[2][1];
  double d12 = u1[0]*u2[0]+u1[1]*u2[1]+u1[2]*u2[2];
#pragma unroll
  for (int i3=0;i3<3;i3++) u2[i3] -= d12*u1[i3];
  double n2 = 1.0/sqrt(fmax(u2[0]*u2[0]+u2[1]*u2[1]+u2[2]*u2[2], 1e-300));
#pragma unroll
  for (int i3=0;i3<3;i3++) u2[i3] *= n2;
  u3[0] = u1[1]*u2[2] - u1[2]*u2[1];
  u3[1] = u1[2]*u2[0] - u1[0]*u2[2];
  u3[2] = u1[0]*u2[1] - u1[1]*u2[0];
  // U W V^T = [u2,-u1,u3] V^T ;  U W^T V^T = [-u2,u1,u3] V^T
  double R1a[9], R2a[9];
#pragma unroll
  for (int i3=0;i3<3;i3++)
#pragma unroll
    for (int j3=0;j3<3;j3++) {
      double m  = u3[i3]*Vv[j3][2];
      double pA = u2[i3]*Vv[j3][0] - u1[i3]*Vv[j3][1];
      R1a[i3*3+j3] = pA + m;
      R2a[i3*3+j3] = m - pA;
    }
  double det1 = R1a[0]*(R1a[4]*R1a[8]-R1a[5]*R1a[7])
              - R1a[1]*(R1a[3]*R1a[8]-R1a[5]*R1a[6])
              + R1a[2]*(R1a[3]*R1a[7]-R1a[4]*R1a[6]);
  double det2 = R2a[0]*(R2a[4]*R2a[8]-R2a[5]*R2a[7])
              - R2a[1]*(R2a[3]*R2a[8]-R2a[5]*R2a[6])
              + R2a[2]*(R2a[3]*R2a[7]-R2a[4]*R2a[6]);
  double sg1 = (det1 < 0.0) ? -1.0 : 1.0;
  double sg2 = (det2 < 0.0) ? -1.0 : 1.0;

  float* o = Rws + (size_t)b*21;
#pragma unroll
  for (int j=0;j<9;j++) { o[j] = (float)(sg1*R1a[j]); o[9+j] = (float)(sg2*R2a[j]); }
  o[18] = (float)u3[0]; o[19] = (float)u3[1]; o[20] = (float)u3[2];
}

// ===========================================================================
// K3: cheirality scoring (fp32) + argmax + assemble T01/T10
// grid 256 x 512
// ===========================================================================
#define K3_T   512
#define K3_PPT (NPTS / K3_T)

__global__ __launch_bounds__(K3_T, 2)
void k3_score(const float* __restrict__ kpts0,
              const float* __restrict__ kpts1,
              const float* __restrict__ conf,
              const float* __restrict__ t_scale,
              const float* __restrict__ Kmat,
              const float* __restrict__ Rws,
              float* __restrict__ out)
{
  const int b    = blockIdx.x;
  const int tid  = threadIdx.x;
  const int lane = tid & 63;
  const int wv   = tid >> 6;

  __shared__ float sscore[K3_T/64][4];

  double Kd[9];
  float Ki0[9], Ki1[9];
  inv3x3d(Kmat + (size_t)b*18, Kd);
#pragma unroll
  for (int j=0;j<9;j++) Ki0[j] = (float)Kd[j];
  inv3x3d(Kmat + (size_t)b*18 + 9, Kd);
#pragma unroll
  for (int j=0;j<9;j++) Ki1[j] = (float)Kd[j];

  const float* rb = Rws + (size_t)b*21;
  float r1[9], r2[9], tv[3];
#pragma unroll
  for (int j=0;j<9;j++) { r1[j] = rb[j]; r2[j] = rb[9+j]; }
  tv[0] = rb[18]; tv[1] = rb[19]; tv[2] = rb[20];

  const float2* k0p = (const float2*)kpts0 + (size_t)b*NPTS;
  const float2* k1p = (const float2*)kpts1 + (size_t)b*NPTS;
  const float*  cp  = conf + (size_t)b*NPTS;

  float sc[4] = {0.f, 0.f, 0.f, 0.f};
  for (int p=0;p<K3_PPT;p++) {
    const int i = tid + p*K3_T;
    const float2 q0 = k0p[i];
    const float2 q1 = k1p[i];
    const float  w  = cp[i];
    float x0[3], x1[3];
    x0[0] = fmaf(Ki0[0],q0.x, fmaf(Ki0[1],q0.y, Ki0[2]));
    x0[1] = fmaf(Ki0[3],q0.x, fmaf(Ki0[4],q0.y, Ki0[5]));
    x0[2] = fmaf(Ki0[6],q0.x, fmaf(Ki0[7],q0.y, Ki0[8]));
    x1[0] = fmaf(Ki1[0],q1.x, fmaf(Ki1[1],q1.y, Ki1[2]));
    x1[1] = fmaf(Ki1[3],q1.x, fmaf(Ki1[4],q1.y, Ki1[5]));
    x1[2] = fmaf(Ki1[6],q1.x, fmaf(Ki1[7],q1.y, Ki1[8]));
    const float bb2 = x1[0]*x1[0]+x1[1]*x1[1]+x1[2]*x1[2];
    const float bt  = x1[0]*tv[0]+x1[1]*tv[1]+x1[2]*tv[2];
    {
      float a0 = r1[0]*x0[0]+r1[1]*x0[1]+r1[2]*x0[2];
      float a1 = r1[3]*x0[0]+r1[4]*x0[1]+r1[5]*x0[2];
      float a2 = r1[6]*x0[0]+r1[7]*x0[1]+r1[8]*x0[2];
      float aa = a0*a0+a1*a1+a2*a2;
      float ab = a0*x1[0]+a1*x1[1]+a2*x1[2];
      float at = a0*tv[0]+a1*tv[1]+a2*tv[2];
      float n0v = ab*bt - at*bb2;   // d0*det, det>0
      float n1v = aa*bt - ab*at;    // d1*det
      if (n0v > 0.f && n1v > 0.f) sc[0] += w;   // (R1,+t)
      if (n0v < 0.f && n1v < 0.f) sc[1] += w;   // (R1,-t)
    }
    {
      float a0 = r2[0]*x0[0]+r2[1]*x0[1]+r2[2]*x0[2];
      float a1 = r2[3]*x0[0]+r2[4]*x0[1]+r2[5]*x0[2];
      float a2 = r2[6]*x0[0]+r2[7]*x0[1]+r2[8]*x0[2];
      float aa = a0*a0+a1*a1+a2*a2;
      float ab = a0*x1[0]+a1*x1[1]+a2*x1[2];
      float at = a0*tv[0]+a1*tv[1]+a2*tv[2];
      float n0v = ab*bt - at*bb2;
      float n1v = aa*bt - ab*at;
      if (n0v > 0.f && n1v > 0.f) sc[2] += w;   // (R2,+t)
      if (n0v < 0.f && n1v < 0.f) sc[3] += w;   // (R2,-t)
    }
  }
#pragma unroll
  for (int c=0;c<4;c++) {
    float vv = sc[c];
#pragma unroll
    for (int off=32; off>0; off>>=1) vv += __shfl_xor(vv, off, 64);
    sc[c] = vv;
  }
  if (lane == 0) {
#pragma unroll
    for (int c=0;c<4;c++) sscore[wv][c] = sc[c];
  }
  __syncthreads();

  if (tid == 0) {
    float st[4];
#pragma unroll
    for (int c=0;c<4;c++) {
      float s = 0.f;
#pragma unroll
      for (int wq=0; wq<K3_T/64; wq++) s += sscore[wq][c];
      st[c] = s;
    }
    int bestc = 0; float bs = st[0];
    if (st[1] > bs) { bs = st[1]; bestc = 1; }   // strict > keeps first on tie
    if (st[2] > bs) { bs = st[2]; bestc = 2; }
    if (st[3] > bs) { bs = st[3]; bestc = 3; }
    float Rb[9];
#pragma unroll
    for (int j=0;j<9;j++) Rb[j] = (bestc < 2) ? r1[j] : r2[j];
    const float sg = (bestc & 1) ? -1.f : 1.f;
    const float ts = t_scale[(size_t)b*2];
    const float t0 = sg*tv[0]*ts, t1 = sg*tv[1]*ts, t2 = sg*tv[2]*ts;
    float* o = out + (size_t)b*32;
    // T01 = [R | t_sc ; 0 0 0 1]
    o[0]=Rb[0]; o[1]=Rb[1]; o[2] =Rb[2]; o[3] =t0;
    o[4]=Rb[3]; o[5]=Rb[4]; o[6] =Rb[5]; o[7] =t1;
    o[8]=Rb[6]; o[9]=Rb[7]; o[10]=Rb[8]; o[11]=t2;
    o[12]=0.f; o[13]=0.f; o[14]=0.f; o[15]=1.f;
    // T10 = [R^T | -R^T t_sc ; 0 0 0 1]
    const float ti0 = -(Rb[0]*t0 + Rb[3]*t1 + Rb[6]*t2);
    const float ti1 = -(Rb[1]*t0 + Rb[4]*t1 + Rb[7]*t2);
    const float ti2 = -(Rb[2]*t0 + Rb[5]*t1 + Rb[8]*t2);
    o[16]=Rb[0]; o[17]=Rb[3]; o[18]=Rb[6]; o[19]=ti0;
    o[20]=Rb[1]; o[21]=Rb[4]; o[22]=Rb[7]; o[23]=ti1;
    o[24]=Rb[2]; o[25]=Rb[5]; o[26]=Rb[8]; o[27]=ti2;
    o[28]=0.f; o[29]=0.f; o[30]=0.f; o[31]=1.f;
  }
}

// ===========================================================================
extern "C" void kernel_launch(void* const* d_in, const int* in_sizes, int n_in,
                              void* d_out, int out_size, void* d_ws, size_t ws_size,
                              hipStream_t stream) {
  (void)in_sizes; (void)n_in; (void)out_size; (void)ws_size;
  const float* kpts0  = (const float*)d_in[0];
  const float* kpts1  = (const float*)d_in[1];
  const float* conf   = (const float*)d_in[2];
  const float* tscale = (const float*)d_in[3];
  const float* K      = (const float*)d_in[4];
  float* outp = (float*)d_out;

  double* Mws = (double*)d_ws;                                    // 256*45*8 = 92160 B
  float*  Rws = (float*)((char*)d_ws + (size_t)NBATCH*45*8);      // 256*21*4 = 21504 B

  k1_reduce<<<dim3(NBATCH), dim3(K1_T), 0, stream>>>(kpts0, kpts1, conf, K, Mws);
  k2_solve <<<dim3(NBATCH/64), dim3(64), 0, stream>>>(Mws, Rws);
  k3_score <<<dim3(NBATCH), dim3(K3_T), 0, stream>>>(kpts0, kpts1, conf, tscale, K, Rws, outp);
}

// Round 3
// 98.235 us; speedup vs baseline: 1.1287x; 1.0360x over previous
//
#include <hip/hip_runtime.h>
#include <math.h>

#define NBATCH 256
#define NPTS   4096
#define NT     512
#define PPT    (NPTS / NT)
#define NWAVE  (NT / 64)

// packed-lower index, r >= c
#define IDX(r,c)   ((r)*((r)+1)/2+(c))
// packed-upper index (reduction storage order), r <= c
#define UPIDX(r,c) ((r)*9 - ((r)*((r)-1))/2 + ((c)-(r)))

// fp64-internal 3x3 inverse of fp32 K, result to fp32
__device__ __forceinline__ void inv3x3f(const float* __restrict__ Km, float* Ki) {
  double a = Km[0], bb = Km[1], c = Km[2];
  double d = Km[3], e  = Km[4], f = Km[5];
  double g = Km[6], h  = Km[7], i = Km[8];
  double C00 =  e*i - f*h;
  double C01 = -(d*i - f*g);
  double C02 =  d*h - e*g;
  double det = a*C00 + bb*C01 + c*C02;
  double rd = 1.0/det;
  Ki[0] = (float)(C00*rd); Ki[1] = (float)(-(bb*i - c*h)*rd); Ki[2] = (float)( (bb*f - c*e)*rd);
  Ki[3] = (float)(C01*rd); Ki[4] = (float)( (a*i  - c*g)*rd); Ki[5] = (float)(-(a*f  - c*d)*rd);
  Ki[6] = (float)(C02*rd); Ki[7] = (float)(-(a*h - bb*g)*rd); Ki[8] = (float)( (a*e  - bb*d)*rd);
}

// ===========================================================================
// Fused: block b = batch b. Phase1 fp32 reduce M -> solve on tid0 (fp64,
// in-place single packed array, no spills) -> phase3 fp32 scoring (L2-hot
// re-read of the same 80KB this block just fetched) -> assemble.
// ===========================================================================
__global__ __launch_bounds__(NT, 1)
void pose_fused(const float* __restrict__ kpts0,
                const float* __restrict__ kpts1,
                const float* __restrict__ conf,
                const float* __restrict__ t_scale,
                const float* __restrict__ Kmat,
                float* __restrict__ out)
{
  const int b    = blockIdx.x;
  const int tid  = threadIdx.x;
  const int lane = tid & 63;
  const int wv   = tid >> 6;

  __shared__ float  red[NWAVE][45];
  __shared__ double sMd[45];
  __shared__ float  sR[21];           // R1(9), R2(9), t(3) as fp32
  __shared__ float  sscore[NWAVE][4];

  float Ki0[9], Ki1[9];
  inv3x3f(Kmat + (size_t)b*18,     Ki0);
  inv3x3f(Kmat + (size_t)b*18 + 9, Ki1);

  const float2* k0p = (const float2*)kpts0 + (size_t)b*NPTS;
  const float2* k1p = (const float2*)kpts1 + (size_t)b*NPTS;
  const float*  cp  = conf + (size_t)b*NPTS;

  // ---------------- Phase 1: M = sum_n w * X X^T (fp32 partials) -----------
  float acc[45];
#pragma unroll
  for (int j=0;j<45;j++) acc[j] = 0.f;

#pragma unroll
  for (int p=0;p<PPT;p++) {
    const int i = tid + p*NT;
    const float2 q0 = k0p[i];
    const float2 q1 = k1p[i];
    const float  w  = cp[i];
    float x0[3], x1[3];
    x0[0] = fmaf(Ki0[0],q0.x, fmaf(Ki0[1],q0.y, Ki0[2]));
    x0[1] = fmaf(Ki0[3],q0.x, fmaf(Ki0[4],q0.y, Ki0[5]));
    x0[2] = fmaf(Ki0[6],q0.x, fmaf(Ki0[7],q0.y, Ki0[8]));
    x1[0] = fmaf(Ki1[0],q1.x, fmaf(Ki1[1],q1.y, Ki1[2]));
    x1[1] = fmaf(Ki1[3],q1.x, fmaf(Ki1[4],q1.y, Ki1[5]));
    x1[2] = fmaf(Ki1[6],q1.x, fmaf(Ki1[7],q1.y, Ki1[8]));
    float X[9], wX[9];
#pragma unroll
    for (int ii=0; ii<3; ii++)
#pragma unroll
      for (int jj=0; jj<3; jj++)
        X[ii*3+jj] = x1[ii]*x0[jj];
#pragma unroll
    for (int j=0;j<9;j++) wX[j] = w*X[j];
    int k = 0;
#pragma unroll
    for (int r=0;r<9;r++)
#pragma unroll
      for (int c=r;c<9;c++) { acc[k] = fmaf(wX[r], X[c], acc[k]); k++; }
  }

#pragma unroll
  for (int j=0;j<45;j++) {
    float v = acc[j];
#pragma unroll
    for (int off=32; off>0; off>>=1) v += __shfl_xor(v, off, 64);
    acc[j] = v;
  }
  if (lane == 0) {
#pragma unroll
    for (int j=0;j<45;j++) red[wv][j] = acc[j];
  }
  __syncthreads();
  if (tid < 45) {
    double s = 0.0;
#pragma unroll
    for (int wq=0; wq<NWAVE; wq++) s += (double)red[wq][tid];
    sMd[tid] = s;
  }
  __syncthreads();

  // ---------------- Phase 2 (tid 0): eig-min -> E -> SVD -> candidates -----
  if (tid == 0) {
    // load packed-lower from packed-upper storage
    double L[45];
#pragma unroll
    for (int r=0;r<9;r++)
#pragma unroll
      for (int c=0;c<=r;c++)
        L[IDX(r,c)] = sMd[UPIDX(c,r)];

    // Cholesky M = L L^T (packed lower, in place). M is PD (lmin ~ 12).
    double dinv[9];
#pragma unroll
    for (int k=0;k<9;k++) {
      double s = L[IDX(k,k)];
#pragma unroll
      for (int j=0;j<k;j++) s -= L[IDX(k,j)]*L[IDX(k,j)];
      double l = sqrt(fmax(s, 1e-30));
      L[IDX(k,k)] = l;
      dinv[k] = 1.0/l;
#pragma unroll
      for (int i2=k+1;i2<9;i2++) {
        double s2 = L[IDX(i2,k)];
#pragma unroll
        for (int j=0;j<k;j++) s2 -= L[IDX(i2,j)]*L[IDX(k,j)];
        L[IDX(i2,k)] = s2*dinv[k];
      }
    }

    // W = L^{-1} IN PLACE. Column j ascending, row i ascending:
    // reads L[i][k] (k in (j,i): columns >j, untouched) and W[k][j]
    // (already-overwritten column j), writes over L[i][j] after its read.
#pragma unroll
    for (int j=0;j<9;j++) {
#pragma unroll
      for (int i2=j+1;i2<9;i2++) {
        double s = L[IDX(i2,j)]*dinv[j];           // k=j term, W[j][j]=dinv[j]
#pragma unroll
        for (int k=j+1;k<i2;k++) s += L[IDX(i2,k)]*L[IDX(k,j)];
        L[IDX(i2,j)] = -s*dinv[i2];
      }
    }
#pragma unroll
    for (int j=0;j<9;j++) L[IDX(j,j)] = dinv[j];   // W diagonal

    // B = W^T W = M^{-1} IN PLACE. Row i ascending via temp row:
    // B row i uses only W rows >= i; rows < i (already B) never referenced.
#pragma unroll
    for (int i2=0;i2<9;i2++) {
      double tmp[9];
#pragma unroll
      for (int j=0;j<=i2;j++) {
        double s = 0.0;
#pragma unroll
        for (int k=i2;k<9;k++) s += L[IDX(k,i2)]*L[IDX(k,j)];
        tmp[j] = s;
      }
#pragma unroll
      for (int j=0;j<=i2;j++) L[IDX(i2,j)] = tmp[j];
    }

    // power iteration on B (= inverse iteration on M); (lmin/l2)^20 ~ 1e-5.
    // no renorm needed: fp64 exponent absorbs the ~lmin^-1 per-iter shrink.
    double v[9];
#pragma unroll
    for (int j=0;j<9;j++) v[j] = 0.125;
    v[4] = 1.0;
    for (int it=0; it<20; it++) {
      double y[9];
#pragma unroll
      for (int i2=0;i2<9;i2++) {
        double s = 0.0;
#pragma unroll
        for (int j=0;j<9;j++) {
          const int rr = (i2>j)?i2:j, cc = (i2>j)?j:i2;
          s = fma(L[IDX(rr,cc)], v[j], s);
        }
        y[i2] = s;
      }
#pragma unroll
      for (int j=0;j<9;j++) v[j] = y[j];
    }
    {
      double nn = 0.0;
#pragma unroll
      for (int j=0;j<9;j++) nn += v[j]*v[j];
      double rn = 1.0/sqrt(nn);
#pragma unroll
      for (int j=0;j<9;j++) v[j] *= rn;
    }

    // E = reshape(v,3,3); SVD via Jacobi on G=E^T E (V), U by projection+cross
    double E0[3][3];
#pragma unroll
    for (int ii=0;ii<3;ii++)
#pragma unroll
      for (int jj=0;jj<3;jj++) E0[ii][jj] = v[ii*3+jj];
    double G[3][3];
#pragma unroll
    for (int a2=0;a2<3;a2++)
#pragma unroll
      for (int b2=0;b2<3;b2++)
        G[a2][b2] = E0[0][a2]*E0[0][b2] + E0[1][a2]*E0[1][b2] + E0[2][a2]*E0[2][b2];
    double Vv[3][3] = {{1,0,0},{0,1,0},{0,0,1}};
#define JROT(P,Q,RR) do { \
      double apq = G[P][Q]; \
      if (fabs(apq) > 1e-300) { \
        double app = G[P][P], aqq = G[Q][Q]; \
        double tau = (aqq - app) / (2.0*apq); \
        double tt = ((tau >= 0.0) ? 1.0 : -1.0) / (fabs(tau) + sqrt(1.0 + tau*tau)); \
        double cc_ = 1.0/sqrt(1.0 + tt*tt); \
        double ss_ = tt*cc_; \
        G[P][P] = app - tt*apq; \
        G[Q][Q] = aqq + tt*apq; \
        G[P][Q] = 0.0; G[Q][P] = 0.0; \
        double grp = G[RR][P], grq = G[RR][Q]; \
        G[RR][P] = cc_*grp - ss_*grq; G[P][RR] = G[RR][P]; \
        G[RR][Q] = ss_*grp + cc_*grq; G[Q][RR] = G[RR][Q]; \
        double v0p = Vv[0][P], v0q = Vv[0][Q]; \
        Vv[0][P] = cc_*v0p - ss_*v0q; Vv[0][Q] = ss_*v0p + cc_*v0q; \
        double v1p = Vv[1][P], v1q = Vv[1][Q]; \
        Vv[1][P] = cc_*v1p - ss_*v1q; Vv[1][Q] = ss_*v1p + cc_*v1q; \
        double v2p = Vv[2][P], v2q = Vv[2][Q]; \
        Vv[2][P] = cc_*v2p - ss_*v2q; Vv[2][Q] = ss_*v2p + cc_*v2q; \
      } } while(0)
    for (int sw=0; sw<6; sw++) { JROT(0,1,2); JROT(0,2,1); JROT(1,2,0); }
#undef JROT
    double lam[3] = {G[0][0], G[1][1], G[2][2]};
#define CSWAP(A_,B_) if (lam[A_] < lam[B_]) { \
      double tl = lam[A_]; lam[A_] = lam[B_]; lam[B_] = tl; \
      double t0_ = Vv[0][A_]; Vv[0][A_] = Vv[0][B_]; Vv[0][B_] = t0_; \
      double t1_ = Vv[1][A_]; Vv[1][A_] = Vv[1][B_]; Vv[1][B_] = t1_; \
      double t2_ = Vv[2][A_]; Vv[2][A_] = Vv[2][B_]; Vv[2][B_] = t2_; }
    CSWAP(0,1); CSWAP(0,2); CSWAP(1,2);
#undef CSWAP
    double u1[3], u2[3], u3[3];
#pragma unroll
    for (int i3=0;i3<3;i3++)
      u1[i3] = E0[i3][0]*Vv[0][0] + E0[i3][1]*Vv[1][0] + E0[i3][2]*Vv[2][0];
    double n1 = 1.0/sqrt(fmax(u1[0]*u1[0]+u1[1]*u1[1]+u1[2]*u1[2], 1e-300));
#pragma unroll
    for (int i3=0;i3<3;i3++) u1[i3] *= n1;
#pragma unroll
    for (int i3=0;i3<3;i3++)
      u2[i3] = E0[i3][0]*Vv[0][1] + E0[i3][1]*Vv[1][1] + E0[i3][2]*Vv[2][1];
    double d12 = u1[0]*u2[0]+u1[1]*u2[1]+u1[2]*u2[2];
#pragma unroll
    for (int i3=0;i3<3;i3++) u2[i3] -= d12*u1[i3];
    double n2 = 1.0/sqrt(fmax(u2[0]*u2[0]+u2[1]*u2[1]+u2[2]*u2[2], 1e-300));
#pragma unroll
    for (int i3=0;i3<3;i3++) u2[i3] *= n2;
    u3[0] = u1[1]*u2[2] - u1[2]*u2[1];
    u3[1] = u1[2]*u2[0] - u1[0]*u2[2];
    u3[2] = u1[0]*u2[1] - u1[1]*u2[0];
    // U W V^T = [u2,-u1,u3] V^T ;  U W^T V^T = [-u2,u1,u3] V^T
    double R1a[9], R2a[9];
#pragma unroll
    for (int i3=0;i3<3;i3++)
#pragma unroll
      for (int j3=0;j3<3;j3++) {
        double m  = u3[i3]*Vv[j3][2];
        double pA = u2[i3]*Vv[j3][0] - u1[i3]*Vv[j3][1];
        R1a[i3*3+j3] = pA + m;
        R2a[i3*3+j3] = m - pA;
      }
    double det1 = R1a[0]*(R1a[4]*R1a[8]-R1a[5]*R1a[7])
                - R1a[1]*(R1a[3]*R1a[8]-R1a[5]*R1a[6])
                + R1a[2]*(R1a[3]*R1a[7]-R1a[4]*R1a[6]);
    double det2 = R2a[0]*(R2a[4]*R2a[8]-R2a[5]*R2a[7])
                - R2a[1]*(R2a[3]*R2a[8]-R2a[5]*R2a[6])
                + R2a[2]*(R2a[3]*R2a[7]-R2a[4]*R2a[6]);
    double sg1 = (det1 < 0.0) ? -1.0 : 1.0;
    double sg2 = (det2 < 0.0) ? -1.0 : 1.0;
#pragma unroll
    for (int j3=0;j3<9;j3++) { sR[j3] = (float)(sg1*R1a[j3]); sR[9+j3] = (float)(sg2*R2a[j3]); }
    sR[18] = (float)u3[0]; sR[19] = (float)u3[1]; sR[20] = (float)u3[2];
  }
  __syncthreads();

  // ---------------- Phase 3: fp32 cheirality scores (L2-hot re-read) -------
  float r1[9], r2[9], tv[3];
#pragma unroll
  for (int j=0;j<9;j++) { r1[j] = sR[j]; r2[j] = sR[9+j]; }
  tv[0] = sR[18]; tv[1] = sR[19]; tv[2] = sR[20];

  float sc[4] = {0.f, 0.f, 0.f, 0.f};
#pragma unroll
  for (int p=0;p<PPT;p++) {
    const int i = tid + p*NT;
    const float2 q0 = k0p[i];
    const float2 q1 = k1p[i];
    const float  w  = cp[i];
    float x0[3], x1[3];
    x0[0] = fmaf(Ki0[0],q0.x, fmaf(Ki0[1],q0.y, Ki0[2]));
    x0[1] = fmaf(Ki0[3],q0.x, fmaf(Ki0[4],q0.y, Ki0[5]));
    x0[2] = fmaf(Ki0[6],q0.x, fmaf(Ki0[7],q0.y, Ki0[8]));
    x1[0] = fmaf(Ki1[0],q1.x, fmaf(Ki1[1],q1.y, Ki1[2]));
    x1[1] = fmaf(Ki1[3],q1.x, fmaf(Ki1[4],q1.y, Ki1[5]));
    x1[2] = fmaf(Ki1[6],q1.x, fmaf(Ki1[7],q1.y, Ki1[8]));
    const float bb2 = x1[0]*x1[0]+x1[1]*x1[1]+x1[2]*x1[2];
    const float bt  = x1[0]*tv[0]+x1[1]*tv[1]+x1[2]*tv[2];
    {
      float a0 = r1[0]*x0[0]+r1[1]*x0[1]+r1[2]*x0[2];
      float a1 = r1[3]*x0[0]+r1[4]*x0[1]+r1[5]*x0[2];
      float a2 = r1[6]*x0[0]+r1[7]*x0[1]+r1[8]*x0[2];
      float aa = a0*a0+a1*a1+a2*a2;
      float ab = a0*x1[0]+a1*x1[1]+a2*x1[2];
      float at = a0*tv[0]+a1*tv[1]+a2*tv[2];
      float n0v = ab*bt - at*bb2;   // d0*det (det>0)
      float n1v = aa*bt - ab*at;    // d1*det
      if (n0v > 0.f && n1v > 0.f) sc[0] += w;   // (R1,+t)
      if (n0v < 0.f && n1v < 0.f) sc[1] += w;   // (R1,-t)
    }
    {
      float a0 = r2[0]*x0[0]+r2[1]*x0[1]+r2[2]*x0[2];
      float a1 = r2[3]*x0[0]+r2[4]*x0[1]+r2[5]*x0[2];
      float a2 = r2[6]*x0[0]+r2[7]*x0[1]+r2[8]*x0[2];
      float aa = a0*a0+a1*a1+a2*a2;
      float ab = a0*x1[0]+a1*x1[1]+a2*x1[2];
      float at = a0*tv[0]+a1*tv[1]+a2*tv[2];
      float n0v = ab*bt - at*bb2;
      float n1v = aa*bt - ab*at;
      if (n0v > 0.f && n1v > 0.f) sc[2] += w;   // (R2,+t)
      if (n0v < 0.f && n1v < 0.f) sc[3] += w;   // (R2,-t)
    }
  }
#pragma unroll
  for (int c=0;c<4;c++) {
    float vv = sc[c];
#pragma unroll
    for (int off=32; off>0; off>>=1) vv += __shfl_xor(vv, off, 64);
    sc[c] = vv;
  }
  if (lane == 0) {
#pragma unroll
    for (int c=0;c<4;c++) sscore[wv][c] = sc[c];
  }
  __syncthreads();

  // ---------------- Phase 4 (tid 0): argmax + assemble T01/T10 -------------
  if (tid == 0) {
    float st[4];
#pragma unroll
    for (int c=0;c<4;c++) {
      float s = 0.f;
#pragma unroll
      for (int wq=0; wq<NWAVE; wq++) s += sscore[wq][c];
      st[c] = s;
    }
    int bestc = 0; float bs = st[0];
    if (st[1] > bs) { bs = st[1]; bestc = 1; }   // strict > keeps first on tie
    if (st[2] > bs) { bs = st[2]; bestc = 2; }
    if (st[3] > bs) { bs = st[3]; bestc = 3; }
    float Rb[9];
#pragma unroll
    for (int j=0;j<9;j++) Rb[j] = (bestc < 2) ? r1[j] : r2[j];
    const float sg = (bestc & 1) ? -1.f : 1.f;
    const float ts = t_scale[(size_t)b*2];
    const float t0 = sg*tv[0]*ts, t1 = sg*tv[1]*ts, t2 = sg*tv[2]*ts;
    float* o = out + (size_t)b*32;
    // T01 = [R | t_sc ; 0 0 0 1]
    o[0]=Rb[0]; o[1]=Rb[1]; o[2] =Rb[2]; o[3] =t0;
    o[4]=Rb[3]; o[5]=Rb[4]; o[6] =Rb[5]; o[7] =t1;
    o[8]=Rb[6]; o[9]=Rb[7]; o[10]=Rb[8]; o[11]=t2;
    o[12]=0.f; o[13]=0.f; o[14]=0.f; o[15]=1.f;
    // T10 = [R^T | -R^T t_sc ; 0 0 0 1]
    const float ti0 = -(Rb[0]*t0 + Rb[3]*t1 + Rb[6]*t2);
    const float ti1 = -(Rb[1]*t0 + Rb[4]*t1 + Rb[7]*t2);
    const float ti2 = -(Rb[2]*t0 + Rb[5]*t1 + Rb[8]*t2);
    o[16]=Rb[0]; o[17]=Rb[3]; o[18]=Rb[6]; o[19]=ti0;
    o[20]=Rb[1]; o[21]=Rb[4]; o[22]=Rb[7]; o[23]=ti1;
    o[24]=Rb[2]; o[25]=Rb[5]; o[26]=Rb[8]; o[27]=ti2;
    o[28]=0.f; o[29]=0.f; o[30]=0.f; o[31]=1.f;
  }
}

// ===========================================================================
extern "C" void kernel_launch(void* const* d_in, const int* in_sizes, int n_in,
                              void* d_out, int out_size, void* d_ws, size_t ws_size,
                              hipStream_t stream) {
  (void)in_sizes; (void)n_in; (void)out_size; (void)d_ws; (void)ws_size;
  const float* kpts0  = (const float*)d_in[0];
  const float* kpts1  = (const float*)d_in[1];
  const float* conf   = (const float*)d_in[2];
  const float* tscale = (const float*)d_in[3];
  const float* K      = (const float*)d_in[4];
  float* outp = (float*)d_out;
  pose_fused<<<dim3(NBATCH), dim3(NT), 0, stream>>>(kpts0, kpts1, conf, tscale, K, outp);
}

// Round 5
// 97.895 us; speedup vs baseline: 1.1326x; 1.0035x over previous
//
#include <hip/hip_runtime.h>
#include <math.h>

#define NBATCH 256
#define NPTS   4096
#define NT     512
#define PPT    (NPTS / NT)          // 8 points per thread
#define NWAVE  (NT / 64)

// packed-lower index, r >= c
#define IDX(r,c)   ((r)*((r)+1)/2+(c))
// packed-upper index (reduction storage order), r <= c
#define UPIDX(r,c) ((r)*9 - ((r)*((r)-1))/2 + ((c)-(r)))

// fp64-internal 3x3 inverse of fp32 K, result to fp32
__device__ __forceinline__ void inv3x3f(const float* __restrict__ Km, float* Ki) {
  double a = Km[0], bb = Km[1], c = Km[2];
  double d = Km[3], e  = Km[4], f = Km[5];
  double g = Km[6], h  = Km[7], i = Km[8];
  double C00 =  e*i - f*h;
  double C01 = -(d*i - f*g);
  double C02 =  d*h - e*g;
  double det = a*C00 + bb*C01 + c*C02;
  double rd = 1.0/det;
  Ki[0] = (float)(C00*rd); Ki[1] = (float)(-(bb*i - c*h)*rd); Ki[2] = (float)( (bb*f - c*e)*rd);
  Ki[3] = (float)(C01*rd); Ki[4] = (float)( (a*i  - c*g)*rd); Ki[5] = (float)(-(a*f  - c*d)*rd);
  Ki[6] = (float)(C02*rd); Ki[7] = (float)(-(a*h - bb*g)*rd); Ki[8] = (float)( (a*e  - bb*d)*rd);
}

// ===========================================================================
// Fused, single-pass: block b = batch b.
//  Phase 1: float4 loads, normalize once, KEEP x0/x1/w in registers (fp32),
//           fp32 reduce of M -> fp64 cross-wave combine.
//  Phase 2: tid0, fp64 solve (R3-proven: Cholesky -> L^-1 -> M^-1 in one
//           packed array -> 20 power iters -> 3x3 Jacobi SVD).
//  Phase 3: cheirality scores from REGISTERS (no second global pass).
//  Phase 4: argmax + assemble T01/T10.
// ===========================================================================
__global__ __launch_bounds__(NT, 1)
void pose_fused(const float* __restrict__ kpts0,
                const float* __restrict__ kpts1,
                const float* __restrict__ conf,
                const float* __restrict__ t_scale,
                const float* __restrict__ Kmat,
                float* __restrict__ out)
{
  const int b    = blockIdx.x;
  const int tid  = threadIdx.x;
  const int lane = tid & 63;
  const int wv   = tid >> 6;

  __shared__ float  red[NWAVE][45];
  __shared__ double sMd[45];
  __shared__ float  sR[21];           // R1(9), R2(9), t(3)
  __shared__ float  sscore[NWAVE][4];

  float Ki0[9], Ki1[9];
  inv3x3f(Kmat + (size_t)b*18,     Ki0);
  inv3x3f(Kmat + (size_t)b*18 + 9, Ki1);

  const float4* k0p4 = (const float4*)(kpts0 + (size_t)b*NPTS*2);
  const float4* k1p4 = (const float4*)(kpts1 + (size_t)b*NPTS*2);
  const float2* cp2  = (const float2*)(conf  + (size_t)b*NPTS);

  // ---------------- Phase 1: load+normalize once, reduce M -----------------
  float px0[PPT][3], px1[PPT][3], pw[PPT];   // kept live into phase 3
  float acc[45];
#pragma unroll
  for (int j=0;j<45;j++) acc[j] = 0.f;

#pragma unroll
  for (int p=0;p<PPT/2;p++) {
    const int idx = tid + p*NT;          // float4 index: 2 points
    const float4 q0 = k0p4[idx];
    const float4 q1 = k1p4[idx];
    const float2 w2 = cp2[idx];
#pragma unroll
    for (int h=0; h<2; h++) {
      const int pt = 2*p + h;
      const float u0 = h ? q0.z : q0.x, v0 = h ? q0.w : q0.y;
      const float u1 = h ? q1.z : q1.x, v1 = h ? q1.w : q1.y;
      const float w  = h ? w2.y : w2.x;
      float x0[3], x1[3];
      x0[0] = fmaf(Ki0[0],u0, fmaf(Ki0[1],v0, Ki0[2]));
      x0[1] = fmaf(Ki0[3],u0, fmaf(Ki0[4],v0, Ki0[5]));
      x0[2] = fmaf(Ki0[6],u0, fmaf(Ki0[7],v0, Ki0[8]));
      x1[0] = fmaf(Ki1[0],u1, fmaf(Ki1[1],v1, Ki1[2]));
      x1[1] = fmaf(Ki1[3],u1, fmaf(Ki1[4],v1, Ki1[5]));
      x1[2] = fmaf(Ki1[6],u1, fmaf(Ki1[7],v1, Ki1[8]));
#pragma unroll
      for (int j=0;j<3;j++) { px0[pt][j] = x0[j]; px1[pt][j] = x1[j]; }
      pw[pt] = w;
      float X[9], wX[9];
#pragma unroll
      for (int ii=0; ii<3; ii++)
#pragma unroll
        for (int jj=0; jj<3; jj++)
          X[ii*3+jj] = x1[ii]*x0[jj];
#pragma unroll
      for (int j=0;j<9;j++) wX[j] = w*X[j];
      int k = 0;
#pragma unroll
      for (int r=0;r<9;r++)
#pragma unroll
        for (int c=r;c<9;c++) { acc[k] = fmaf(wX[r], X[c], acc[k]); k++; }
    }
  }

#pragma unroll
  for (int j=0;j<45;j++) {
    float v = acc[j];
#pragma unroll
    for (int off=32; off>0; off>>=1) v += __shfl_xor(v, off, 64);
    acc[j] = v;
  }
  if (lane == 0) {
#pragma unroll
    for (int j=0;j<45;j++) red[wv][j] = acc[j];
  }
  __syncthreads();
  if (tid < 45) {
    double s = 0.0;
#pragma unroll
    for (int wq=0; wq<NWAVE; wq++) s += (double)red[wq][tid];
    sMd[tid] = s;
  }
  __syncthreads();

  // ---------------- Phase 2 (tid 0): fp64 solve (R3-proven) ----------------
  if (tid == 0) {
    double L[45];
#pragma unroll
    for (int r=0;r<9;r++)
#pragma unroll
      for (int c=0;c<=r;c++)
        L[IDX(r,c)] = sMd[UPIDX(c,r)];

    // Cholesky M = L L^T (packed lower, in place). M PD (lmin ~ 12).
    double dinv[9];
#pragma unroll
    for (int k=0;k<9;k++) {
      double s = L[IDX(k,k)];
#pragma unroll
      for (int j=0;j<k;j++) s -= L[IDX(k,j)]*L[IDX(k,j)];
      double l = sqrt(fmax(s, 1e-30));
      L[IDX(k,k)] = l;
      dinv[k] = 1.0/l;
#pragma unroll
      for (int i2=k+1;i2<9;i2++) {
        double s2 = L[IDX(i2,k)];
#pragma unroll
        for (int j=0;j<k;j++) s2 -= L[IDX(i2,j)]*L[IDX(k,j)];
        L[IDX(i2,k)] = s2*dinv[k];
      }
    }

    // W = L^{-1} in place (col j asc, row i asc).
#pragma unroll
    for (int j=0;j<9;j++) {
#pragma unroll
      for (int i2=j+1;i2<9;i2++) {
        double s = L[IDX(i2,j)]*dinv[j];
#pragma unroll
        for (int k=j+1;k<i2;k++) s += L[IDX(i2,k)]*L[IDX(k,j)];
        L[IDX(i2,j)] = -s*dinv[i2];
      }
    }
#pragma unroll
    for (int j=0;j<9;j++) L[IDX(j,j)] = dinv[j];

    // B = W^T W = M^{-1} in place (row i asc; uses W rows >= i only).
#pragma unroll
    for (int i2=0;i2<9;i2++) {
      double tmp[9];
#pragma unroll
      for (int j=0;j<=i2;j++) {
        double s = 0.0;
#pragma unroll
        for (int k=i2;k<9;k++) s += L[IDX(k,i2)]*L[IDX(k,j)];
        tmp[j] = s;
      }
#pragma unroll
      for (int j=0;j<=i2;j++) L[IDX(i2,j)] = tmp[j];
    }

    // power iteration on B = inverse iteration on M; (lmin/l2)^20 ~ 1e-5.
    // no renorm: fp64 exponent absorbs the per-iter shrink.
    double v[9];
#pragma unroll
    for (int j=0;j<9;j++) v[j] = 0.125;
    v[4] = 1.0;
    for (int it=0; it<20; it++) {
      double y[9];
#pragma unroll
      for (int i2=0;i2<9;i2++) {
        double s = 0.0;
#pragma unroll
        for (int j=0;j<9;j++) {
          const int rr = (i2>j)?i2:j, cc = (i2>j)?j:i2;
          s = fma(L[IDX(rr,cc)], v[j], s);
        }
        y[i2] = s;
      }
#pragma unroll
      for (int j=0;j<9;j++) v[j] = y[j];
    }
    {
      double nn = 0.0;
#pragma unroll
      for (int j=0;j<9;j++) nn += v[j]*v[j];
      double rn = 1.0/sqrt(nn);
#pragma unroll
      for (int j=0;j<9;j++) v[j] *= rn;
    }

    // E = reshape(v,3,3); SVD: Jacobi on G=E^T E -> V; U via projection+cross
    double E0[3][3];
#pragma unroll
    for (int ii=0;ii<3;ii++)
#pragma unroll
      for (int jj=0;jj<3;jj++) E0[ii][jj] = v[ii*3+jj];
    double G[3][3];
#pragma unroll
    for (int a2=0;a2<3;a2++)
#pragma unroll
      for (int b2=0;b2<3;b2++)
        G[a2][b2] = E0[0][a2]*E0[0][b2] + E0[1][a2]*E0[1][b2] + E0[2][a2]*E0[2][b2];
    double Vv[3][3] = {{1,0,0},{0,1,0},{0,0,1}};
#define JROT(P,Q,RR) do { \
      double apq = G[P][Q]; \
      if (fabs(apq) > 1e-300) { \
        double app = G[P][P], aqq = G[Q][Q]; \
        double tau = (aqq - app) / (2.0*apq); \
        double tt = ((tau >= 0.0) ? 1.0 : -1.0) / (fabs(tau) + sqrt(1.0 + tau*tau)); \
        double cc_ = 1.0/sqrt(1.0 + tt*tt); \
        double ss_ = tt*cc_; \
        G[P][P] = app - tt*apq; \
        G[Q][Q] = aqq + tt*apq; \
        G[P][Q] = 0.0; G[Q][P] = 0.0; \
        double grp = G[RR][P], grq = G[RR][Q]; \
        G[RR][P] = cc_*grp - ss_*grq; G[P][RR] = G[RR][P]; \
        G[RR][Q] = ss_*grp + cc_*grq; G[Q][RR] = G[RR][Q]; \
        double v0p = Vv[0][P], v0q = Vv[0][Q]; \
        Vv[0][P] = cc_*v0p - ss_*v0q; Vv[0][Q] = ss_*v0p + cc_*v0q; \
        double v1p = Vv[1][P], v1q = Vv[1][Q]; \
        Vv[1][P] = cc_*v1p - ss_*v1q; Vv[1][Q] = ss_*v1p + cc_*v1q; \
        double v2p = Vv[2][P], v2q = Vv[2][Q]; \
        Vv[2][P] = cc_*v2p - ss_*v2q; Vv[2][Q] = ss_*v2p + cc_*v2q; \
      } } while(0)
    for (int sw=0; sw<6; sw++) { JROT(0,1,2); JROT(0,2,1); JROT(1,2,0); }
#undef JROT
    double lam[3] = {G[0][0], G[1][1], G[2][2]};
#define CSWAP(A_,B_) if (lam[A_] < lam[B_]) { \
      double tl = lam[A_]; lam[A_] = lam[B_]; lam[B_] = tl; \
      double t0_ = Vv[0][A_]; Vv[0][A_] = Vv[0][B_]; Vv[0][B_] = t0_; \
      double t1_ = Vv[1][A_]; Vv[1][A_] = Vv[1][B_]; Vv[1][B_] = t1_; \
      double t2_ = Vv[2][A_]; Vv[2][A_] = Vv[2][B_]; Vv[2][B_] = t2_; }
    CSWAP(0,1); CSWAP(0,2); CSWAP(1,2);
#undef CSWAP
    double u1[3], u2[3], u3[3];
#pragma unroll
    for (int i3=0;i3<3;i3++)
      u1[i3] = E0[i3][0]*Vv[0][0] + E0[i3][1]*Vv[1][0] + E0[i3][2]*Vv[2][0];
    double n1 = 1.0/sqrt(fmax(u1[0]*u1[0]+u1[1]*u1[1]+u1[2]*u1[2], 1e-300));
#pragma unroll
    for (int i3=0;i3<3;i3++) u1[i3] *= n1;
#pragma unroll
    for (int i3=0;i3<3;i3++)
      u2[i3] = E0[i3][0]*Vv[0][1] + E0[i3][1]*Vv[1][1] + E0[i3][2]*Vv[2][1];
    double d12 = u1[0]*u2[0]+u1[1]*u2[1]+u1[2]*u2[2];
#pragma unroll
    for (int i3=0;i3<3;i3++) u2[i3] -= d12*u1[i3];
    double n2 = 1.0/sqrt(fmax(u2[0]*u2[0]+u2[1]*u2[1]+u2[2]*u2[2], 1e-300));
#pragma unroll
    for (int i3=0;i3<3;i3++) u2[i3] *= n2;
    u3[0] = u1[1]*u2[2] - u1[2]*u2[1];
    u3[1] = u1[2]*u2[0] - u1[0]*u2[2];
    u3[2] = u1[0]*u2[1] - u1[1]*u2[0];
    // U W V^T = [u2,-u1,u3] V^T ;  U W^T V^T = [-u2,u1,u3] V^T
    double R1a[9], R2a[9];
#pragma unroll
    for (int i3=0;i3<3;i3++)
#pragma unroll
      for (int j3=0;j3<3;j3++) {
        double m  = u3[i3]*Vv[j3][2];
        double pA = u2[i3]*Vv[j3][0] - u1[i3]*Vv[j3][1];
        R1a[i3*3+j3] = pA + m;
        R2a[i3*3+j3] = m - pA;
      }
    double det1 = R1a[0]*(R1a[4]*R1a[8]-R1a[5]*R1a[7])
                - R1a[1]*(R1a[3]*R1a[8]-R1a[5]*R1a[6])
                + R1a[2]*(R1a[3]*R1a[7]-R1a[4]*R1a[6]);
    double det2 = R2a[0]*(R2a[4]*R2a[8]-R2a[5]*R2a[7])
                - R2a[1]*(R2a[3]*R2a[8]-R2a[5]*R2a[6])
                + R2a[2]*(R2a[3]*R2a[7]-R2a[4]*R2a[6]);
    double sg1 = (det1 < 0.0) ? -1.0 : 1.0;
    double sg2 = (det2 < 0.0) ? -1.0 : 1.0;
#pragma unroll
    for (int j3=0;j3<9;j3++) { sR[j3] = (float)(sg1*R1a[j3]); sR[9+j3] = (float)(sg2*R2a[j3]); }
    sR[18] = (float)u3[0]; sR[19] = (float)u3[1]; sR[20] = (float)u3[2];
  }
  __syncthreads();

  // ---------------- Phase 3: cheirality scores from registers --------------
  float r1[9], r2[9], tv[3];
#pragma unroll
  for (int j=0;j<9;j++) { r1[j] = sR[j]; r2[j] = sR[9+j]; }
  tv[0] = sR[18]; tv[1] = sR[19]; tv[2] = sR[20];

  float sc[4] = {0.f, 0.f, 0.f, 0.f};
#pragma unroll
  for (int p=0;p<PPT;p++) {
    const float x00 = px0[p][0], x01 = px0[p][1], x02 = px0[p][2];
    const float x10 = px1[p][0], x11 = px1[p][1], x12 = px1[p][2];
    const float w   = pw[p];
    const float bb2 = x10*x10 + x11*x11 + x12*x12;
    const float bt  = x10*tv[0] + x11*tv[1] + x12*tv[2];
    {
      float a0 = r1[0]*x00 + r1[1]*x01 + r1[2]*x02;
      float a1 = r1[3]*x00 + r1[4]*x01 + r1[5]*x02;
      float a2 = r1[6]*x00 + r1[7]*x01 + r1[8]*x02;
      float aa = a0*a0 + a1*a1 + a2*a2;
      float ab = a0*x10 + a1*x11 + a2*x12;
      float at = a0*tv[0] + a1*tv[1] + a2*tv[2];
      float n0v = ab*bt - at*bb2;     // d0*det (det>0)
      float n1v = aa*bt - ab*at;      // d1*det
      if (n0v > 0.f && n1v > 0.f) sc[0] += w;    // (R1,+t)
      if (n0v < 0.f && n1v < 0.f) sc[1] += w;    // (R1,-t)
    }
    {
      float a0 = r2[0]*x00 + r2[1]*x01 + r2[2]*x02;
      float a1 = r2[3]*x00 + r2[4]*x01 + r2[5]*x02;
      float a2 = r2[6]*x00 + r2[7]*x01 + r2[8]*x02;
      float aa = a0*a0 + a1*a1 + a2*a2;
      float ab = a0*x10 + a1*x11 + a2*x12;
      float at = a0*tv[0] + a1*tv[1] + a2*tv[2];
      float n0v = ab*bt - at*bb2;
      float n1v = aa*bt - ab*at;
      if (n0v > 0.f && n1v > 0.f) sc[2] += w;    // (R2,+t)
      if (n0v < 0.f && n1v < 0.f) sc[3] += w;    // (R2,-t)
    }
  }
#pragma unroll
  for (int c=0;c<4;c++) {
    float vv = sc[c];
#pragma unroll
    for (int off=32; off>0; off>>=1) vv += __shfl_xor(vv, off, 64);
    sc[c] = vv;
  }
  if (lane == 0) {
#pragma unroll
    for (int c=0;c<4;c++) sscore[wv][c] = sc[c];
  }
  __syncthreads();

  // ---------------- Phase 4 (tid 0): argmax + assemble T01/T10 -------------
  if (tid == 0) {
    float st[4];
#pragma unroll
    for (int c=0;c<4;c++) {
      float s = 0.f;
#pragma unroll
      for (int wq=0; wq<NWAVE; wq++) s += sscore[wq][c];
      st[c] = s;
    }
    int bestc = 0; float bs = st[0];
    if (st[1] > bs) { bs = st[1]; bestc = 1; }   // strict > keeps first on tie
    if (st[2] > bs) { bs = st[2]; bestc = 2; }
    if (st[3] > bs) { bs = st[3]; bestc = 3; }
    float Rb[9];
#pragma unroll
    for (int j=0;j<9;j++) Rb[j] = (bestc < 2) ? r1[j] : r2[j];
    const float sg = (bestc & 1) ? -1.f : 1.f;
    const float ts = t_scale[(size_t)b*2];
    const float t0 = sg*tv[0]*ts, t1 = sg*tv[1]*ts, t2 = sg*tv[2]*ts;
    float* o = out + (size_t)b*32;
    // T01 = [R | t_sc ; 0 0 0 1]
    o[0]=Rb[0]; o[1]=Rb[1]; o[2] =Rb[2]; o[3] =t0;
    o[4]=Rb[3]; o[5]=Rb[4]; o[6] =Rb[5]; o[7] =t1;
    o[8]=Rb[6]; o[9]=Rb[7]; o[10]=Rb[8]; o[11]=t2;
    o[12]=0.f; o[13]=0.f; o[14]=0.f; o[15]=1.f;
    // T10 = [R^T | -R^T t_sc ; 0 0 0 1]
    const float ti0 = -(Rb[0]*t0 + Rb[3]*t1 + Rb[6]*t2);
    const float ti1 = -(Rb[1]*t0 + Rb[4]*t1 + Rb[7]*t2);
    const float ti2 = -(Rb[2]*t0 + Rb[5]*t1 + Rb[8]*t2);
    o[16]=Rb[0]; o[17]=Rb[3]; o[18]=Rb[6]; o[19]=ti0;
    o[20]=Rb[1]; o[21]=Rb[4]; o[22]=Rb[7]; o[23]=ti1;
    o[24]=Rb[2]; o[25]=Rb[5]; o[26]=Rb[8]; o[27]=ti2;
    o[28]=0.f; o[29]=0.f; o[30]=0.f; o[31]=1.f;
  }
}

// ===========================================================================
extern "C" void kernel_launch(void* const* d_in, const int* in_sizes, int n_in,
                              void* d_out, int out_size, void* d_ws, size_t ws_size,
                              hipStream_t stream) {
  (void)in_sizes; (void)n_in; (void)out_size; (void)d_ws; (void)ws_size;
  const float* kpts0  = (const float*)d_in[0];
  const float* kpts1  = (const float*)d_in[1];
  const float* conf   = (const float*)d_in[2];
  const float* tscale = (const float*)d_in[3];
  const float* K      = (const float*)d_in[4];
  float* outp = (float*)d_out;
  pose_fused<<<dim3(NBATCH), dim3(NT), 0, stream>>>(kpts0, kpts1, conf, tscale, K, outp);
}

// Round 7
// 97.344 us; speedup vs baseline: 1.1390x; 1.0057x over previous
//
#include <hip/hip_runtime.h>
#include <math.h>

#define NBATCH 256
#define NPTS   4096
#define NT     512
#define PPT    (NPTS / NT)          // 8 points per thread
#define NWAVE  (NT / 64)

// packed-lower index, r >= c
#define IDX(r,c)   ((r)*((r)+1)/2+(c))
// packed-upper index (reduction storage order), r <= c
#define UPIDX(r,c) ((r)*9 - ((r)*((r)-1))/2 + ((c)-(r)))

// fp64-internal 3x3 inverse of fp32 K, result to fp32
__device__ __forceinline__ void inv3x3f(const float* __restrict__ Km, float* Ki) {
  double a = Km[0], bb = Km[1], c = Km[2];
  double d = Km[3], e  = Km[4], f = Km[5];
  double g = Km[6], h  = Km[7], i = Km[8];
  double C00 =  e*i - f*h;
  double C01 = -(d*i - f*g);
  double C02 =  d*h - e*g;
  double det = a*C00 + bb*C01 + c*C02;
  double rd = 1.0/det;
  Ki[0] = (float)(C00*rd); Ki[1] = (float)(-(bb*i - c*h)*rd); Ki[2] = (float)( (bb*f - c*e)*rd);
  Ki[3] = (float)(C01*rd); Ki[4] = (float)( (a*i  - c*g)*rd); Ki[5] = (float)(-(a*f  - c*d)*rd);
  Ki[6] = (float)(C02*rd); Ki[7] = (float)(-(a*h - bb*g)*rd); Ki[8] = (float)( (a*e  - bb*d)*rd);
}

// ===========================================================================
// Fused, single-pass: block b = batch b.
//  Phase 1: float4 loads, normalize once, KEEP x0/x1/w in registers (fp32),
//           fp32 reduce of M -> fp64 cross-wave combine.
//  Phase 2: tid0, fp64 solve (proven: Cholesky -> L^-1 -> M^-1 in one
//           packed array -> 20 power iters -> 6-sweep fp64 Jacobi SVD).
//           NOTE: R4 (fp32 solve) and R6 (closed-form eig) both flipped the
//           candidate argmax in near-tie batches -> absmax ~2. Do not touch.
//  Phase 3: cheirality scores from REGISTERS (no second global pass).
//  Phase 4: argmax + assemble T01/T10.
// ===========================================================================
__global__ __launch_bounds__(NT, 1)
void pose_fused(const float* __restrict__ kpts0,
                const float* __restrict__ kpts1,
                const float* __restrict__ conf,
                const float* __restrict__ t_scale,
                const float* __restrict__ Kmat,
                float* __restrict__ out)
{
  const int b    = blockIdx.x;
  const int tid  = threadIdx.x;
  const int lane = tid & 63;
  const int wv   = tid >> 6;

  __shared__ float  red[NWAVE][45];
  __shared__ double sMd[45];
  __shared__ float  sR[21];           // R1(9), R2(9), t(3)
  __shared__ float  sscore[NWAVE][4];

  float Ki0[9], Ki1[9];
  inv3x3f(Kmat + (size_t)b*18,     Ki0);
  inv3x3f(Kmat + (size_t)b*18 + 9, Ki1);

  const float4* k0p4 = (const float4*)(kpts0 + (size_t)b*NPTS*2);
  const float4* k1p4 = (const float4*)(kpts1 + (size_t)b*NPTS*2);
  const float2* cp2  = (const float2*)(conf  + (size_t)b*NPTS);

  // ---------------- Phase 1: load+normalize once, reduce M -----------------
  float px0[PPT][3], px1[PPT][3], pw[PPT];   // kept live into phase 3
  float acc[45];
#pragma unroll
  for (int j=0;j<45;j++) acc[j] = 0.f;

#pragma unroll
  for (int p=0;p<PPT/2;p++) {
    const int idx = tid + p*NT;          // float4 index: 2 points
    const float4 q0 = k0p4[idx];
    const float4 q1 = k1p4[idx];
    const float2 w2 = cp2[idx];
#pragma unroll
    for (int h=0; h<2; h++) {
      const int pt = 2*p + h;
      const float u0 = h ? q0.z : q0.x, v0 = h ? q0.w : q0.y;
      const float u1 = h ? q1.z : q1.x, v1 = h ? q1.w : q1.y;
      const float w  = h ? w2.y : w2.x;
      float x0[3], x1[3];
      x0[0] = fmaf(Ki0[0],u0, fmaf(Ki0[1],v0, Ki0[2]));
      x0[1] = fmaf(Ki0[3],u0, fmaf(Ki0[4],v0, Ki0[5]));
      x0[2] = fmaf(Ki0[6],u0, fmaf(Ki0[7],v0, Ki0[8]));
      x1[0] = fmaf(Ki1[0],u1, fmaf(Ki1[1],v1, Ki1[2]));
      x1[1] = fmaf(Ki1[3],u1, fmaf(Ki1[4],v1, Ki1[5]));
      x1[2] = fmaf(Ki1[6],u1, fmaf(Ki1[7],v1, Ki1[8]));
#pragma unroll
      for (int j=0;j<3;j++) { px0[pt][j] = x0[j]; px1[pt][j] = x1[j]; }
      pw[pt] = w;
      float X[9], wX[9];
#pragma unroll
      for (int ii=0; ii<3; ii++)
#pragma unroll
        for (int jj=0; jj<3; jj++)
          X[ii*3+jj] = x1[ii]*x0[jj];
#pragma unroll
      for (int j=0;j<9;j++) wX[j] = w*X[j];
      int k = 0;
#pragma unroll
      for (int r=0;r<9;r++)
#pragma unroll
        for (int c=r;c<9;c++) { acc[k] = fmaf(wX[r], X[c], acc[k]); k++; }
    }
  }

#pragma unroll
  for (int j=0;j<45;j++) {
    float v = acc[j];
#pragma unroll
    for (int off=32; off>0; off>>=1) v += __shfl_xor(v, off, 64);
    acc[j] = v;
  }
  if (lane == 0) {
#pragma unroll
    for (int j=0;j<45;j++) red[wv][j] = acc[j];
  }
  __syncthreads();
  if (tid < 45) {
    double s = 0.0;
#pragma unroll
    for (int wq=0; wq<NWAVE; wq++) s += (double)red[wq][tid];
    sMd[tid] = s;
  }
  __syncthreads();

  // ---------------- Phase 2 (tid 0): fp64 solve (proven) -------------------
  if (tid == 0) {
    double L[45];
#pragma unroll
    for (int r=0;r<9;r++)
#pragma unroll
      for (int c=0;c<=r;c++)
        L[IDX(r,c)] = sMd[UPIDX(c,r)];

    // Cholesky M = L L^T (packed lower, in place). M PD (lmin ~ 12).
    double dinv[9];
#pragma unroll
    for (int k=0;k<9;k++) {
      double s = L[IDX(k,k)];
#pragma unroll
      for (int j=0;j<k;j++) s -= L[IDX(k,j)]*L[IDX(k,j)];
      double l = sqrt(fmax(s, 1e-30));
      L[IDX(k,k)] = l;
      dinv[k] = 1.0/l;
#pragma unroll
      for (int i2=k+1;i2<9;i2++) {
        double s2 = L[IDX(i2,k)];
#pragma unroll
        for (int j=0;j<k;j++) s2 -= L[IDX(i2,j)]*L[IDX(k,j)];
        L[IDX(i2,k)] = s2*dinv[k];
      }
    }

    // W = L^{-1} in place (col j asc, row i asc).
#pragma unroll
    for (int j=0;j<9;j++) {
#pragma unroll
      for (int i2=j+1;i2<9;i2++) {
        double s = L[IDX(i2,j)]*dinv[j];
#pragma unroll
        for (int k=j+1;k<i2;k++) s += L[IDX(i2,k)]*L[IDX(k,j)];
        L[IDX(i2,j)] = -s*dinv[i2];
      }
    }
#pragma unroll
    for (int j=0;j<9;j++) L[IDX(j,j)] = dinv[j];

    // B = W^T W = M^{-1} in place (row i asc; uses W rows >= i only).
#pragma unroll
    for (int i2=0;i2<9;i2++) {
      double tmp[9];
#pragma unroll
      for (int j=0;j<=i2;j++) {
        double s = 0.0;
#pragma unroll
        for (int k=i2;k<9;k++) s += L[IDX(k,i2)]*L[IDX(k,j)];
        tmp[j] = s;
      }
#pragma unroll
      for (int j=0;j<=i2;j++) L[IDX(i2,j)] = tmp[j];
    }

    // power iteration on B = inverse iteration on M; (lmin/l2)^20 ~ 1e-5.
    // no renorm: fp64 exponent absorbs the per-iter shrink.
    double v[9];
#pragma unroll
    for (int j=0;j<9;j++) v[j] = 0.125;
    v[4] = 1.0;
    for (int it=0; it<20; it++) {
      double y[9];
#pragma unroll
      for (int i2=0;i2<9;i2++) {
        double s = 0.0;
#pragma unroll
        for (int j=0;j<9;j++) {
          const int rr = (i2>j)?i2:j, cc = (i2>j)?j:i2;
          s = fma(L[IDX(rr,cc)], v[j], s);
        }
        y[i2] = s;
      }
#pragma unroll
      for (int j=0;j<9;j++) v[j] = y[j];
    }
    {
      double nn = 0.0;
#pragma unroll
      for (int j=0;j<9;j++) nn += v[j]*v[j];
      double rn = 1.0/sqrt(nn);
#pragma unroll
      for (int j=0;j<9;j++) v[j] *= rn;
    }

    // E = reshape(v,3,3); SVD: Jacobi on G=E^T E -> V; U via projection+cross
    double E0[3][3];
#pragma unroll
    for (int ii=0;ii<3;ii++)
#pragma unroll
      for (int jj=0;jj<3;jj++) E0[ii][jj] = v[ii*3+jj];
    double G[3][3];
#pragma unroll
    for (int a2=0;a2<3;a2++)
#pragma unroll
      for (int b2=0;b2<3;b2++)
        G[a2][b2] = E0[0][a2]*E0[0][b2] + E0[1][a2]*E0[1][b2] + E0[2][a2]*E0[2][b2];
    double Vv[3][3] = {{1,0,0},{0,1,0},{0,0,1}};
#define JROT(P,Q,RR) do { \
      double apq = G[P][Q]; \
      if (fabs(apq) > 1e-300) { \
        double app = G[P][P], aqq = G[Q][Q]; \
        double tau = (aqq - app) / (2.0*apq); \
        double tt = ((tau >= 0.0) ? 1.0 : -1.0) / (fabs(tau) + sqrt(1.0 + tau*tau)); \
        double cc_ = 1.0/sqrt(1.0 + tt*tt); \
        double ss_ = tt*cc_; \
        G[P][P] = app - tt*apq; \
        G[Q][Q] = aqq + tt*apq; \
        G[P][Q] = 0.0; G[Q][P] = 0.0; \
        double grp = G[RR][P], grq = G[RR][Q]; \
        G[RR][P] = cc_*grp - ss_*grq; G[P][RR] = G[RR][P]; \
        G[RR][Q] = ss_*grp + cc_*grq; G[Q][RR] = G[RR][Q]; \
        double v0p = Vv[0][P], v0q = Vv[0][Q]; \
        Vv[0][P] = cc_*v0p - ss_*v0q; Vv[0][Q] = ss_*v0p + cc_*v0q; \
        double v1p = Vv[1][P], v1q = Vv[1][Q]; \
        Vv[1][P] = cc_*v1p - ss_*v1q; Vv[1][Q] = ss_*v1p + cc_*v1q; \
        double v2p = Vv[2][P], v2q = Vv[2][Q]; \
        Vv[2][P] = cc_*v2p - ss_*v2q; Vv[2][Q] = ss_*v2p + cc_*v2q; \
      } } while(0)
    for (int sw=0; sw<6; sw++) { JROT(0,1,2); JROT(0,2,1); JROT(1,2,0); }
#undef JROT
    double lam[3] = {G[0][0], G[1][1], G[2][2]};
#define CSWAP(A_,B_) if (lam[A_] < lam[B_]) { \
      double tl = lam[A_]; lam[A_] = lam[B_]; lam[B_] = tl; \
      double t0_ = Vv[0][A_]; Vv[0][A_] = Vv[0][B_]; Vv[0][B_] = t0_; \
      double t1_ = Vv[1][A_]; Vv[1][A_] = Vv[1][B_]; Vv[1][B_] = t1_; \
      double t2_ = Vv[2][A_]; Vv[2][A_] = Vv[2][B_]; Vv[2][B_] = t2_; }
    CSWAP(0,1); CSWAP(0,2); CSWAP(1,2);
#undef CSWAP
    double u1[3], u2[3], u3[3];
#pragma unroll
    for (int i3=0;i3<3;i3++)
      u1[i3] = E0[i3][0]*Vv[0][0] + E0[i3][1]*Vv[1][0] + E0[i3][2]*Vv[2][0];
    double n1 = 1.0/sqrt(fmax(u1[0]*u1[0]+u1[1]*u1[1]+u1[2]*u1[2], 1e-300));
#pragma unroll
    for (int i3=0;i3<3;i3++) u1[i3] *= n1;
#pragma unroll
    for (int i3=0;i3<3;i3++)
      u2[i3] = E0[i3][0]*Vv[0][1] + E0[i3][1]*Vv[1][1] + E0[i3][2]*Vv[2][1];
    double d12 = u1[0]*u2[0]+u1[1]*u2[1]+u1[2]*u2[2];
#pragma unroll
    for (int i3=0;i3<3;i3++) u2[i3] -= d12*u1[i3];
    double n2 = 1.0/sqrt(fmax(u2[0]*u2[0]+u2[1]*u2[1]+u2[2]*u2[2], 1e-300));
#pragma unroll
    for (int i3=0;i3<3;i3++) u2[i3] *= n2;
    u3[0] = u1[1]*u2[2] - u1[2]*u2[1];
    u3[1] = u1[2]*u2[0] - u1[0]*u2[2];
    u3[2] = u1[0]*u2[1] - u1[1]*u2[0];
    // U W V^T = [u2,-u1,u3] V^T ;  U W^T V^T = [-u2,u1,u3] V^T
    double R1a[9], R2a[9];
#pragma unroll
    for (int i3=0;i3<3;i3++)
#pragma unroll
      for (int j3=0;j3<3;j3++) {
        double m  = u3[i3]*Vv[j3][2];
        double pA = u2[i3]*Vv[j3][0] - u1[i3]*Vv[j3][1];
        R1a[i3*3+j3] = pA + m;
        R2a[i3*3+j3] = m - pA;
      }
    double det1 = R1a[0]*(R1a[4]*R1a[8]-R1a[5]*R1a[7])
                - R1a[1]*(R1a[3]*R1a[8]-R1a[5]*R1a[6])
                + R1a[2]*(R1a[3]*R1a[7]-R1a[4]*R1a[6]);
    double det2 = R2a[0]*(R2a[4]*R2a[8]-R2a[5]*R2a[7])
                - R2a[1]*(R2a[3]*R2a[8]-R2a[5]*R2a[6])
                + R2a[2]*(R2a[3]*R2a[7]-R2a[4]*R2a[6]);
    double sg1 = (det1 < 0.0) ? -1.0 : 1.0;
    double sg2 = (det2 < 0.0) ? -1.0 : 1.0;
#pragma unroll
    for (int j3=0;j3<9;j3++) { sR[j3] = (float)(sg1*R1a[j3]); sR[9+j3] = (float)(sg2*R2a[j3]); }
    sR[18] = (float)u3[0]; sR[19] = (float)u3[1]; sR[20] = (float)u3[2];
  }
  __syncthreads();

  // ---------------- Phase 3: cheirality scores from registers --------------
  float r1[9], r2[9], tv[3];
#pragma unroll
  for (int j=0;j<9;j++) { r1[j] = sR[j]; r2[j] = sR[9+j]; }
  tv[0] = sR[18]; tv[1] = sR[19]; tv[2] = sR[20];

  float sc[4] = {0.f, 0.f, 0.f, 0.f};
#pragma unroll
  for (int p=0;p<PPT;p++) {
    const float x00 = px0[p][0], x01 = px0[p][1], x02 = px0[p][2];
    const float x10 = px1[p][0], x11 = px1[p][1], x12 = px1[p][2];
    const float w   = pw[p];
    const float bb2 = x10*x10 + x11*x11 + x12*x12;
    const float bt  = x10*tv[0] + x11*tv[1] + x12*tv[2];
    {
      float a0 = r1[0]*x00 + r1[1]*x01 + r1[2]*x02;
      float a1 = r1[3]*x00 + r1[4]*x01 + r1[5]*x02;
      float a2 = r1[6]*x00 + r1[7]*x01 + r1[8]*x02;
      float aa = a0*a0 + a1*a1 + a2*a2;
      float ab = a0*x10 + a1*x11 + a2*x12;
      float at = a0*tv[0] + a1*tv[1] + a2*tv[2];
      float n0v = ab*bt - at*bb2;     // d0*det (det>0)
      float n1v = aa*bt - ab*at;      // d1*det
      if (n0v > 0.f && n1v > 0.f) sc[0] += w;    // (R1,+t)
      if (n0v < 0.f && n1v < 0.f) sc[1] += w;    // (R1,-t)
    }
    {
      float a0 = r2[0]*x00 + r2[1]*x01 + r2[2]*x02;
      float a1 = r2[3]*x00 + r2[4]*x01 + r2[5]*x02;
      float a2 = r2[6]*x00 + r2[7]*x01 + r2[8]*x02;
      float aa = a0*a0 + a1*a1 + a2*a2;
      float ab = a0*x10 + a1*x11 + a2*x12;
      float at = a0*tv[0] + a1*tv[1] + a2*tv[2];
      float n0v = ab*bt - at*bb2;
      float n1v = aa*bt - ab*at;
      if (n0v > 0.f && n1v > 0.f) sc[2] += w;    // (R2,+t)
      if (n0v < 0.f && n1v < 0.f) sc[3] += w;    // (R2,-t)
    }
  }
#pragma unroll
  for (int c=0;c<4;c++) {
    float vv = sc[c];
#pragma unroll
    for (int off=32; off>0; off>>=1) vv += __shfl_xor(vv, off, 64);
    sc[c] = vv;
  }
  if (lane == 0) {
#pragma unroll
    for (int c=0;c<4;c++) sscore[wv][c] = sc[c];
  }
  __syncthreads();

  // ---------------- Phase 4 (tid 0): argmax + assemble T01/T10 -------------
  if (tid == 0) {
    float st[4];
#pragma unroll
    for (int c=0;c<4;c++) {
      float s = 0.f;
#pragma unroll
      for (int wq=0; wq<NWAVE; wq++) s += sscore[wq][c];
      st[c] = s;
    }
    int bestc = 0; float bs = st[0];
    if (st[1] > bs) { bs = st[1]; bestc = 1; }   // strict > keeps first on tie
    if (st[2] > bs) { bs = st[2]; bestc = 2; }
    if (st[3] > bs) { bs = st[3]; bestc = 3; }
    float Rb[9];
#pragma unroll
    for (int j=0;j<9;j++) Rb[j] = (bestc < 2) ? r1[j] : r2[j];
    const float sg = (bestc & 1) ? -1.f : 1.f;
    const float ts = t_scale[(size_t)b*2];
    const float t0 = sg*tv[0]*ts, t1 = sg*tv[1]*ts, t2 = sg*tv[2]*ts;
    float* o = out + (size_t)b*32;
    // T01 = [R | t_sc ; 0 0 0 1]
    o[0]=Rb[0]; o[1]=Rb[1]; o[2] =Rb[2]; o[3] =t0;
    o[4]=Rb[3]; o[5]=Rb[4]; o[6] =Rb[5]; o[7] =t1;
    o[8]=Rb[6]; o[9]=Rb[7]; o[10]=Rb[8]; o[11]=t2;
    o[12]=0.f; o[13]=0.f; o[14]=0.f; o[15]=1.f;
    // T10 = [R^T | -R^T t_sc ; 0 0 0 1]
    const float ti0 = -(Rb[0]*t0 + Rb[3]*t1 + Rb[6]*t2);
    const float ti1 = -(Rb[1]*t0 + Rb[4]*t1 + Rb[7]*t2);
    const float ti2 = -(Rb[2]*t0 + Rb[5]*t1 + Rb[8]*t2);
    o[16]=Rb[0]; o[17]=Rb[3]; o[18]=Rb[6]; o[19]=ti0;
    o[20]=Rb[1]; o[21]=Rb[4]; o[22]=Rb[7]; o[23]=ti1;
    o[24]=Rb[2]; o[25]=Rb[5]; o[26]=Rb[8]; o[27]=ti2;
    o[28]=0.f; o[29]=0.f; o[30]=0.f; o[31]=1.f;
  }
}

// ===========================================================================
extern "C" void kernel_launch(void* const* d_in, const int* in_sizes, int n_in,
                              void* d_out, int out_size, void* d_ws, size_t ws_size,
                              hipStream_t stream) {
  (void)in_sizes; (void)n_in; (void)out_size; (void)d_ws; (void)ws_size;
  const float* kpts0  = (const float*)d_in[0];
  const float* kpts1  = (const float*)d_in[1];
  const float* conf   = (const float*)d_in[2];
  const float* tscale = (const float*)d_in[3];
  const float* K      = (const float*)d_in[4];
  float* outp = (float*)d_out;
  pose_fused<<<dim3(NBATCH), dim3(NT), 0, stream>>>(kpts0, kpts1, conf, tscale, K, outp);
}